// Round 6
// baseline (217.357 us; speedup 1.0000x reference)
//
#include <hip/hip_runtime.h>
#include <hip/hip_bf16.h>
#include <hip/hip_fp16.h>

// ---------------- problem constants ----------------
constexpr int NB = 16;       // batch
constexpr int SS = 64;       // seq len
constexpr int BS = 1024;     // NB*SS
constexpr int NN = 500;      // nodes
constexpr int FF = 32;       // gat out features
constexpr int EE = 8000;     // edges (without self loops)
constexpr int ET = 8500;     // edges + self loops
constexpr int KK = 16000;    // NN*FF  (lstm input size)
constexpr int HH = 128;      // lstm hidden
constexpr int GG = 512;      // 4*HH
constexpr int KS = 16;       // K-split for the big GEMM (250 steps of 64k)

typedef __attribute__((ext_vector_type(8))) _Float16 f16x8;
typedef __attribute__((ext_vector_type(4))) float f32x4;

__device__ __forceinline__ void gload_lds16(const void* g, void* l) {
    __builtin_amdgcn_global_load_lds((const __attribute__((address_space(1))) void*)g,
                                     (__attribute__((address_space(3))) void*)l, 16, 0, 0);
}

__device__ __forceinline__ float fast_sigmoid(float x) {
    return __builtin_amdgcn_rcpf(1.f + __expf(-x));
}
__device__ __forceinline__ float fast_tanh(float x) {
    float ax = fabsf(x);
    float t = 1.f - 2.f * __builtin_amdgcn_rcpf(1.f + __expf(2.f * ax));
    return copysignf(t, x);
}

// ---------------- fused prep: transpose_x | whh->fp16 hi/lo | w_ih->fp16 swizzled ----------------
__global__ __launch_bounds__(256) void k_prep(const float* __restrict__ x, float* __restrict__ xt,
                                              const float* __restrict__ whh,
                                              _Float16* __restrict__ whh_hi,
                                              _Float16* __restrict__ whh_lo,
                                              const float* __restrict__ w_ih,
                                              _Float16* __restrict__ w_h) {
    __shared__ float tile[32][33];
    int bid = blockIdx.x;
    int tid = threadIdx.x;
    if (bid < 512) {
        // xt[n][bs] = x[bs][n]
        int n0 = (bid & 15) * 32, bs0 = (bid >> 4) * 32;
        int tx = tid & 31, ty = tid >> 5;  // 32 x 8
#pragma unroll
        for (int i = 0; i < 4; ++i) {
            int n = n0 + tx, bs = bs0 + ty + i * 8;
            tile[ty + i * 8][tx] = (n < NN) ? x[bs * NN + n] : 0.f;
        }
        __syncthreads();
#pragma unroll
        for (int i = 0; i < 4; ++i) {
            int n = n0 + ty + i * 8, bs = bs0 + tx;
            if (n < NN) xt[n * BS + bs] = tile[tx][ty + i * 8];
        }
    } else if (bid < 768) {
        // whh [512][128] fp32 -> hi/lo fp16 planes (same layout)
        int idx = (bid - 512) * 256 + tid;  // 65536
        float v = whh[idx];
        _Float16 hb = (_Float16)v;
        whh_hi[idx] = hb;
        whh_lo[idx] = (_Float16)(v - (float)hb);
    } else {
        // w_h[g][blk*64 + sl*8 + j] = (fp16) w_ih[g][blk*64 + (sl^(g&7))*8 + j]
        int r = bid - 768;            // 0..4095
        int g = r >> 3;               // 512 rows
        int id = (r & 7) * 256 + tid; // 0..2047, 2000 used
        if (id < 2000) {
            int blk = id >> 3, sl = id & 7;
            int srcc = sl ^ (g & 7);
            const float* src = w_ih + (size_t)g * KK + blk * 64 + srcc * 8;
            float4 v0 = *(const float4*)src;
            float4 v1 = *(const float4*)(src + 4);
            union { __half2 h2[4]; uint4 q; } u;
            u.h2[0] = __floats2half2_rn(v0.x, v0.y);
            u.h2[1] = __floats2half2_rn(v0.z, v0.w);
            u.h2[2] = __floats2half2_rn(v1.x, v1.y);
            u.h2[3] = __floats2half2_rn(v1.z, v1.w);
            *(uint4*)(w_h + (size_t)g * KK + blk * 64 + sl * 8) = u.q;
        }
    }
}

// ---------------- fused graph build: count -> scan -> scatter (1 block) ----------------
__global__ __launch_bounds__(512) void k_graph(const int* __restrict__ ei,
                                               const float* __restrict__ gat_w,
                                               const float* __restrict__ a_src,
                                               const float* __restrict__ a_dst,
                                               int* __restrict__ offsets,
                                               int* __restrict__ esrc,
                                               float* __restrict__ scal) {
    __shared__ int cnt[512];
    __shared__ int sc[2][512];
    __shared__ int cur[512];
    int t = threadIdx.x;  // 512
    cnt[t] = 0;
    __syncthreads();
    for (int e = t; e < ET; e += 512) {
        int d = (e < EE) ? ei[EE + e] : (e - EE);
        atomicAdd(&cnt[d], 1);
    }
    __syncthreads();
    sc[0][t] = cnt[t];
    __syncthreads();
    int pb = 0;
    for (int off = 1; off < 512; off <<= 1) {
        int v = sc[pb][t];
        if (t >= off) v += sc[pb][t - off];
        sc[pb ^ 1][t] = v;
        pb ^= 1;
        __syncthreads();
    }
    int excl = sc[pb][t] - cnt[t];
    if (t <= NN) offsets[t] = excl;
    cur[t] = excl;
    if (t == 0) {
        float ws = 0.f, wd = 0.f;
        for (int f = 0; f < FF; ++f) {
            ws += gat_w[f] * a_src[f];
            wd += gat_w[f] * a_dst[f];
        }
        scal[0] = ws;
        scal[1] = wd;
    }
    __syncthreads();
    for (int e = t; e < ET; e += 512) {
        int sidx = (e < EE) ? ei[e] : (e - EE);
        int d = (e < EE) ? ei[EE + e] : (e - EE);
        int pos = atomicAdd(&cur[d], 1);
        esrc[pos] = sidx;
    }
}

// ---------------- GAT: per-(n,bs) edge softmax -> s[n][bs] ----------------
__global__ void k_gat(const float* __restrict__ xt, const int* __restrict__ offsets,
                      const int* __restrict__ esrc, const float* __restrict__ scal,
                      float* __restrict__ s) {
    int n = blockIdx.y;
    int bs = blockIdx.x * 256 + threadIdx.x;
    float ws = scal[0], wd = scal[1];
    float xd = xt[n * BS + bs];
    float wdxd = wd * xd;
    int e0 = offsets[n], e1 = offsets[n + 1];
    float m = -1e30f, den = 0.f, num = 0.f;
    for (int j = e0; j < e1; ++j) {
        int sidx = esrc[j];  // uniform across wave
        float xs = xt[sidx * BS + bs];
        float z = ws * xs + wdxd;
        float l = (z > 0.f) ? z : 0.2f * z;  // leaky_relu 0.2
        if (l > m) {
            float r = __expf(m - l);
            den *= r;
            num *= r;
            m = l;
        }
        float p = __expf(l - m);
        den += p;
        num += p * xs;
    }
    s[n * BS + bs] = num / den;
}

// ---------------- big GEMM via fp16 MFMA ----------------
__global__ __launch_bounds__(256, 2) void k_gemm_mfma(
    const _Float16* __restrict__ w_h, const float* __restrict__ s,
    const float* __restrict__ gat_w, const float* __restrict__ gat_b,
    float* __restrict__ G2) {
    __shared__ __align__(16) _Float16 Bs[2][128 * 64];  // [buf][g][k] swizzled image
    __shared__ float s_lds[2][2][128];                  // [buf][node][bs_local]

    int tid = threadIdx.x;
    int lane = tid & 63;
    int w = tid >> 6;
    int wm = w >> 1, wn = w & 1;
    int bm = blockIdx.x, bn = blockIdx.y, ks = blockIdx.z;
    int bs0 = bm * 128, g0 = bn * 128;
    int step0 = (ks * 250) >> 4;
    int nst = (((ks + 1) * 250) >> 4) - step0;  // 15 or 16

    int fbase = (lane >> 4) * 8;
    float w8[8], b8[8];
#pragma unroll
    for (int j = 0; j < 8; ++j) {
        w8[j] = gat_w[fbase + j];
        b8[j] = gat_b[fbase + j];
    }

    f32x4 acc[4][4] = {};

    auto stageB = [&](int buf, int stepg) {
#pragma unroll
        for (int qq = 0; qq < 4; ++qq) {
            int q = w * 4 + qq;
            int row_local = q * 8 + (lane >> 3);
            int sl = lane & 7;
            const _Float16* srcp = w_h + (size_t)(g0 + row_local) * KK + stepg * 64 + sl * 8;
            gload_lds16(srcp, &Bs[buf][q * 512]);
        }
        int row = tid >> 7, col = tid & 127;
        int n = 2 * stepg + row;
        s_lds[buf][row][col] = s[n * BS + bs0 + col];
    };

    auto compute = [&](int buf) {
#pragma unroll
        for (int kh = 0; kh < 2; ++kh) {
            f16x8 bfrag[4];
#pragma unroll
            for (int fn = 0; fn < 4; ++fn) {
                int grow = wn * 64 + fn * 16 + (lane & 15);
                int c = kh * 4 + (lane >> 4);
                int slot = c ^ (grow & 7);
                bfrag[fn] = *(const f16x8*)&Bs[buf][grow * 64 + slot * 8];
            }
#pragma unroll
            for (int fm = 0; fm < 4; ++fm) {
                float sval = s_lds[buf][kh][wm * 64 + fm * 16 + (lane & 15)];
                union { f16x8 v; __half2 h2[4]; } af;
#pragma unroll
                for (int j2 = 0; j2 < 4; ++j2) {
                    float t0 = fmaf(sval, w8[2 * j2], b8[2 * j2]);
                    float t1 = fmaf(sval, w8[2 * j2 + 1], b8[2 * j2 + 1]);
                    t0 = t0 > 0.f ? t0 : 0.f;
                    t1 = t1 > 0.f ? t1 : 0.f;
                    af.h2[j2] = __floats2half2_rn(t0, t1);
                }
#pragma unroll
                for (int fn = 0; fn < 4; ++fn) {
                    acc[fm][fn] =
                        __builtin_amdgcn_mfma_f32_16x16x32_f16(af.v, bfrag[fn], acc[fm][fn], 0, 0, 0);
                }
            }
        }
    };

    stageB(0, step0);
    __syncthreads();
    for (int t = 0; t < nst; ++t) {
        if (t + 1 < nst) stageB((t + 1) & 1, step0 + t + 1);
        compute(t & 1);
        __syncthreads();
    }

    float* Gks = G2 + (size_t)ks * BS * GG;
#pragma unroll
    for (int fm = 0; fm < 4; ++fm) {
#pragma unroll
        for (int fn = 0; fn < 4; ++fn) {
            int bs = bs0 + wm * 64 + fm * 16 + ((lane >> 4) << 2);
            int g = g0 + wn * 64 + fn * 16 + (lane & 15);
            float* base = Gks + (size_t)bs * GG + g;
#pragma unroll
            for (int r = 0; r < 4; ++r) base[r * GG] = acc[fm][fn][r];
        }
    }
}

// ---------------- reduce K-split partials + biases -> Xg[bs][512] ----------------
__global__ __launch_bounds__(256) void k_reduce(const float* __restrict__ G2,
                                                const float* __restrict__ b_ih,
                                                const float* __restrict__ b_hh,
                                                float* __restrict__ Xg) {
    int idx = blockIdx.x * 256 + threadIdx.x;  // 131072 float4 slots
    int e = idx * 4;
    int g = e & (GG - 1);
    float4 acc = *(const float4*)&b_ih[g];
    float4 bh = *(const float4*)&b_hh[g];
    acc.x += bh.x; acc.y += bh.y; acc.z += bh.z; acc.w += bh.w;
#pragma unroll
    for (int p = 0; p < KS; ++p) {
        float4 v = *(const float4*)&G2[(size_t)p * BS * GG + e];
        acc.x += v.x; acc.y += v.y; acc.z += v.z; acc.w += v.w;
    }
    *(float4*)&Xg[e] = acc;
}

// ---------------- LSTM via MFMA: 1 block, 8 waves, all 16 batches ----------------
// Per step: gates[16b][512g] = h[16b][128] @ Whh[512][128]^T  (hi/lo fp16 x3 split)
// Wave w owns gate-tiles {w, w+8, w+16, w+24} -> each lane holds i,f,g,o for the
// same (batch m, hdim d=w*16+lane&15) in its 4 C-frags; c stays in registers.
__global__ __launch_bounds__(512, 2) void k_lstm_mfma(const float* __restrict__ Xg,
                                                      const _Float16* __restrict__ whh_hi,
                                                      const _Float16* __restrict__ whh_lo,
                                                      const float* __restrict__ head_w,
                                                      const float* __restrict__ head_b,
                                                      float* __restrict__ out) {
    __shared__ __align__(16) _Float16 h_hi[16 * 136];  // [b][k] stride 136
    __shared__ __align__(16) _Float16 h_lo[16 * 136];
    __shared__ __align__(16) float hf[16][132];        // final h fp32 for head

    int tid = threadIdx.x;
    int lane = tid & 63;
    int w = tid >> 6;        // 0..7
    int l15 = lane & 15;
    int lhi = lane >> 4;     // 0..3
    int mbase = lhi * 4;     // C rows (batch) for this lane
    int d = w * 16 + l15;    // hdim owned by this lane

    // Whh B-fragments, resident in VGPRs for the whole recurrence.
    // frag(q, ks): lane holds Whh[g = q*128 + w*16 + l15][ks*32 + lhi*8 + 0..7]
    f16x8 wfh[4][4], wfl[4][4];
#pragma unroll
    for (int q = 0; q < 4; ++q) {
        int g = q * 128 + d;
#pragma unroll
        for (int ks2 = 0; ks2 < 4; ++ks2) {
            int k = ks2 * 32 + lhi * 8;
            wfh[q][ks2] = *(const f16x8*)&whh_hi[g * HH + k];
            wfl[q][ks2] = *(const f16x8*)&whh_lo[g * HH + k];
        }
    }
    for (int i = tid; i < 16 * 136; i += 512) {
        h_hi[i] = (_Float16)0.f;
        h_lo[i] = (_Float16)0.f;
    }
    float c[4] = {0.f, 0.f, 0.f, 0.f};
    __syncthreads();

    for (int t = 0; t < SS; ++t) {
        // Xg prefetch (consumed after MFMA)
        float xg[4][4];
#pragma unroll
        for (int q = 0; q < 4; ++q) {
            int g = q * 128 + d;
#pragma unroll
            for (int r = 0; r < 4; ++r)
                xg[q][r] = Xg[(size_t)((mbase + r) * SS + t) * GG + g];
        }
        // A-fragments from LDS h planes
        f16x8 ah[4], al[4];
#pragma unroll
        for (int ks2 = 0; ks2 < 4; ++ks2) {
            int off = l15 * 136 + ks2 * 32 + lhi * 8;
            ah[ks2] = *(const f16x8*)&h_hi[off];
            al[ks2] = *(const f16x8*)&h_lo[off];
        }
        f32x4 acc[4] = {};
#pragma unroll
        for (int q = 0; q < 4; ++q) {
#pragma unroll
            for (int ks2 = 0; ks2 < 4; ++ks2) {
                acc[q] = __builtin_amdgcn_mfma_f32_16x16x32_f16(ah[ks2], wfh[q][ks2], acc[q], 0, 0, 0);
                acc[q] = __builtin_amdgcn_mfma_f32_16x16x32_f16(ah[ks2], wfl[q][ks2], acc[q], 0, 0, 0);
                acc[q] = __builtin_amdgcn_mfma_f32_16x16x32_f16(al[ks2], wfh[q][ks2], acc[q], 0, 0, 0);
            }
        }
        __syncthreads();  // all A-reads done (acc dependency drains lgkm before barrier)
#pragma unroll
        for (int r = 0; r < 4; ++r) {
            float ig = acc[0][r] + xg[0][r];
            float fg = acc[1][r] + xg[1][r];
            float gg = acc[2][r] + xg[2][r];
            float og = acc[3][r] + xg[3][r];
            float si = fast_sigmoid(ig);
            float sf = fast_sigmoid(fg);
            float so = fast_sigmoid(og);
            c[r] = sf * c[r] + si * fast_tanh(gg);
            float h = so * fast_tanh(c[r]);
            int m = mbase + r;
            _Float16 hh = (_Float16)h;
            h_hi[m * 136 + d] = hh;
            h_lo[m * 136 + d] = (_Float16)(h - (float)hh);
            if (t == SS - 1) hf[m][d] = h;
        }
        __syncthreads();  // new h visible before next step's reads
    }

    // fused head: out[b][n] = head_b[n] + sum_d hf[b][d]*head_w[n][d]
    if (tid < NN) {
        float4 wr4[32];
        const float4* w4 = (const float4*)&head_w[tid * HH];
#pragma unroll
        for (int j4 = 0; j4 < 32; ++j4) wr4[j4] = w4[j4];
        float hb = head_b[tid];
        for (int b = 0; b < NB; ++b) {
            const float4* h4 = (const float4*)&hf[b][0];
            float a0 = 0.f, a1 = 0.f, a2 = 0.f, a3 = 0.f;
#pragma unroll
            for (int j4 = 0; j4 < 32; ++j4) {
                float4 hv = h4[j4];
                float4 wv = wr4[j4];
                a0 = fmaf(wv.x, hv.x, a0);
                a1 = fmaf(wv.y, hv.y, a1);
                a2 = fmaf(wv.z, hv.z, a2);
                a3 = fmaf(wv.w, hv.w, a3);
            }
            out[b * NN + tid] = hb + (a0 + a1) + (a2 + a3);
        }
    }
}

// ---------------- launch ----------------
extern "C" void kernel_launch(void* const* d_in, const int* in_sizes, int n_in, void* d_out,
                              int out_size, void* d_ws, size_t ws_size, hipStream_t stream) {
    const float* x = (const float*)d_in[0];
    const int* ei = (const int*)d_in[1];  // integer inputs arrive as int32
    const float* gat_w = (const float*)d_in[2];
    const float* a_src = (const float*)d_in[3];
    const float* a_dst = (const float*)d_in[4];
    const float* gat_b = (const float*)d_in[5];
    const float* w_ih = (const float*)d_in[6];
    const float* w_hh = (const float*)d_in[7];
    const float* b_ih = (const float*)d_in[8];
    const float* b_hh = (const float*)d_in[9];
    const float* head_w = (const float*)d_in[10];
    const float* head_b = (const float*)d_in[11];
    float* out = (float*)d_out;

    char* ws = (char*)d_ws;
    float* xt = (float*)(ws + 0);                      // 2,048,000 (dead after k_gat)
    float* s = (float*)(ws + 2048000u);                // 2,048,000 (dead after k_gemm)
    float* G2 = (float*)(ws + 4096000u);               // 16*1024*512*4 = 33,554,432
    _Float16* whh_hi = (_Float16*)(ws + 37650432u);    // 131,072
    _Float16* whh_lo = (_Float16*)(ws + 37781504u);    // 131,072
    _Float16* w_h = (_Float16*)(ws + 37912576u);       // 16,384,000
    char* base2 = ws + 54296576u;                      // misc 65,536
    int* offsets = (int*)(base2);
    int* esrc = (int*)(base2 + 4096);
    float* scal = (float*)(base2 + 45056);
    float* Xg = (float*)(ws + 0);                      // 2,097,152 — overlaps xt+s (dead by
                                                       // k_reduce; stream-ordered)

    k_prep<<<4864, 256, 0, stream>>>(x, xt, w_hh, whh_hi, whh_lo, w_ih, w_h);
    k_graph<<<1, 512, 0, stream>>>(ei, gat_w, a_src, a_dst, offsets, esrc, scal);
    k_gat<<<dim3(BS / 256, NN), 256, 0, stream>>>(xt, offsets, esrc, scal, s);
    k_gemm_mfma<<<dim3(8, 4, KS), 256, 0, stream>>>(w_h, s, gat_w, gat_b, G2);
    k_reduce<<<512, 256, 0, stream>>>(G2, b_ih, b_hh, Xg);
    k_lstm_mfma<<<1, 512, 0, stream>>>(Xg, whh_hi, whh_lo, head_w, head_b, out);
}

// Round 7
// 180.591 us; speedup vs baseline: 1.2036x; 1.2036x over previous
//
#include <hip/hip_runtime.h>
#include <hip/hip_bf16.h>
#include <hip/hip_fp16.h>

// ---------------- problem constants ----------------
constexpr int NB = 16;       // batch
constexpr int SS = 64;       // seq len
constexpr int BS = 1024;     // NB*SS
constexpr int NN = 500;      // nodes
constexpr int FF = 32;       // gat out features
constexpr int EE = 8000;     // edges (without self loops)
constexpr int ET = 8500;     // edges + self loops
constexpr int KK = 16000;    // NN*FF  (lstm input size)
constexpr int HH = 128;      // lstm hidden
constexpr int GG = 512;      // 4*HH
constexpr int KS = 16;       // K-split for the big GEMM (250 steps of 64k)

typedef __attribute__((ext_vector_type(8))) _Float16 f16x8;
typedef __attribute__((ext_vector_type(4))) float f32x4;

__device__ __forceinline__ void gload_lds16(const void* g, void* l) {
    __builtin_amdgcn_global_load_lds((const __attribute__((address_space(1))) void*)g,
                                     (__attribute__((address_space(3))) void*)l, 16, 0, 0);
}

__device__ __forceinline__ float fast_sigmoid(float x) {
    return __builtin_amdgcn_rcpf(1.f + __expf(-x));
}
__device__ __forceinline__ float fast_tanh(float x) {
    float ax = fabsf(x);
    float t = 1.f - 2.f * __builtin_amdgcn_rcpf(1.f + __expf(2.f * ax));
    return copysignf(t, x);
}

// ---------------- fused prep: transpose_x | whh->fp16 | w_ih->fp16 swizzled ----------------
__global__ __launch_bounds__(256) void k_prep(const float* __restrict__ x, float* __restrict__ xt,
                                              const float* __restrict__ whh,
                                              _Float16* __restrict__ whh_h,
                                              const float* __restrict__ w_ih,
                                              _Float16* __restrict__ w_h) {
    __shared__ float tile[32][33];
    int bid = blockIdx.x;
    int tid = threadIdx.x;
    if (bid < 512) {
        // xt[n][bs] = x[bs][n]
        int n0 = (bid & 15) * 32, bs0 = (bid >> 4) * 32;
        int tx = tid & 31, ty = tid >> 5;  // 32 x 8
#pragma unroll
        for (int i = 0; i < 4; ++i) {
            int n = n0 + tx, bs = bs0 + ty + i * 8;
            tile[ty + i * 8][tx] = (n < NN) ? x[bs * NN + n] : 0.f;
        }
        __syncthreads();
#pragma unroll
        for (int i = 0; i < 4; ++i) {
            int n = n0 + ty + i * 8, bs = bs0 + tx;
            if (n < NN) xt[n * BS + bs] = tile[tx][ty + i * 8];
        }
    } else if (bid < 768) {
        // whh [512][128] fp32 -> fp16 (same layout)
        int idx = (bid - 512) * 256 + tid;  // 65536
        whh_h[idx] = (_Float16)whh[idx];
    } else {
        // w_h[g][blk*64 + sl*8 + j] = (fp16) w_ih[g][blk*64 + (sl^(g&7))*8 + j]
        int r = bid - 768;            // 0..4095
        int g = r >> 3;               // 512 rows
        int id = (r & 7) * 256 + tid; // 0..2047, 2000 used
        if (id < 2000) {
            int blk = id >> 3, sl = id & 7;
            int srcc = sl ^ (g & 7);
            const float* src = w_ih + (size_t)g * KK + blk * 64 + srcc * 8;
            float4 v0 = *(const float4*)src;
            float4 v1 = *(const float4*)(src + 4);
            union { __half2 h2[4]; uint4 q; } u;
            u.h2[0] = __floats2half2_rn(v0.x, v0.y);
            u.h2[1] = __floats2half2_rn(v0.z, v0.w);
            u.h2[2] = __floats2half2_rn(v1.x, v1.y);
            u.h2[3] = __floats2half2_rn(v1.z, v1.w);
            *(uint4*)(w_h + (size_t)g * KK + blk * 64 + sl * 8) = u.q;
        }
    }
}

// ---------------- fused graph build: count -> scan -> scatter (1 block) ----------------
__global__ __launch_bounds__(512) void k_graph(const int* __restrict__ ei,
                                               const float* __restrict__ gat_w,
                                               const float* __restrict__ a_src,
                                               const float* __restrict__ a_dst,
                                               int* __restrict__ offsets,
                                               int* __restrict__ esrc,
                                               float* __restrict__ scal) {
    __shared__ int cnt[512];
    __shared__ int sc[2][512];
    __shared__ int cur[512];
    int t = threadIdx.x;  // 512
    cnt[t] = 0;
    __syncthreads();
    for (int e = t; e < ET; e += 512) {
        int d = (e < EE) ? ei[EE + e] : (e - EE);
        atomicAdd(&cnt[d], 1);
    }
    __syncthreads();
    sc[0][t] = cnt[t];
    __syncthreads();
    int pb = 0;
    for (int off = 1; off < 512; off <<= 1) {
        int v = sc[pb][t];
        if (t >= off) v += sc[pb][t - off];
        sc[pb ^ 1][t] = v;
        pb ^= 1;
        __syncthreads();
    }
    int excl = sc[pb][t] - cnt[t];
    if (t <= NN) offsets[t] = excl;
    cur[t] = excl;
    if (t == 0) {
        float ws = 0.f, wd = 0.f;
        for (int f = 0; f < FF; ++f) {
            ws += gat_w[f] * a_src[f];
            wd += gat_w[f] * a_dst[f];
        }
        scal[0] = ws;
        scal[1] = wd;
    }
    __syncthreads();
    for (int e = t; e < ET; e += 512) {
        int sidx = (e < EE) ? ei[e] : (e - EE);
        int d = (e < EE) ? ei[EE + e] : (e - EE);
        int pos = atomicAdd(&cur[d], 1);
        esrc[pos] = sidx;
    }
}

// ---------------- GAT: per-(n,bs) edge softmax -> s[n][bs] ----------------
__global__ void k_gat(const float* __restrict__ xt, const int* __restrict__ offsets,
                      const int* __restrict__ esrc, const float* __restrict__ scal,
                      float* __restrict__ s) {
    int n = blockIdx.y;
    int bs = blockIdx.x * 256 + threadIdx.x;
    float ws = scal[0], wd = scal[1];
    float xd = xt[n * BS + bs];
    float wdxd = wd * xd;
    int e0 = offsets[n], e1 = offsets[n + 1];
    float m = -1e30f, den = 0.f, num = 0.f;
    for (int j = e0; j < e1; ++j) {
        int sidx = esrc[j];  // uniform across wave
        float xs = xt[sidx * BS + bs];
        float z = ws * xs + wdxd;
        float l = (z > 0.f) ? z : 0.2f * z;  // leaky_relu 0.2
        if (l > m) {
            float r = __expf(m - l);
            den *= r;
            num *= r;
            m = l;
        }
        float p = __expf(l - m);
        den += p;
        num += p * xs;
    }
    s[n * BS + bs] = num / den;
}

// ---------------- big GEMM via fp16 MFMA ----------------
__global__ __launch_bounds__(256, 2) void k_gemm_mfma(
    const _Float16* __restrict__ w_h, const float* __restrict__ s,
    const float* __restrict__ gat_w, const float* __restrict__ gat_b,
    float* __restrict__ G2) {
    __shared__ __align__(16) _Float16 Bs[2][128 * 64];  // [buf][g][k] swizzled image
    __shared__ float s_lds[2][2][128];                  // [buf][node][bs_local]

    int tid = threadIdx.x;
    int lane = tid & 63;
    int w = tid >> 6;
    int wm = w >> 1, wn = w & 1;
    int bm = blockIdx.x, bn = blockIdx.y, ks = blockIdx.z;
    int bs0 = bm * 128, g0 = bn * 128;
    int step0 = (ks * 250) >> 4;
    int nst = (((ks + 1) * 250) >> 4) - step0;  // 15 or 16

    int fbase = (lane >> 4) * 8;
    float w8[8], b8[8];
#pragma unroll
    for (int j = 0; j < 8; ++j) {
        w8[j] = gat_w[fbase + j];
        b8[j] = gat_b[fbase + j];
    }

    f32x4 acc[4][4] = {};

    auto stageB = [&](int buf, int stepg) {
#pragma unroll
        for (int qq = 0; qq < 4; ++qq) {
            int q = w * 4 + qq;
            int row_local = q * 8 + (lane >> 3);
            int sl = lane & 7;
            const _Float16* srcp = w_h + (size_t)(g0 + row_local) * KK + stepg * 64 + sl * 8;
            gload_lds16(srcp, &Bs[buf][q * 512]);
        }
        int row = tid >> 7, col = tid & 127;
        int n = 2 * stepg + row;
        s_lds[buf][row][col] = s[n * BS + bs0 + col];
    };

    auto compute = [&](int buf) {
#pragma unroll
        for (int kh = 0; kh < 2; ++kh) {
            f16x8 bfrag[4];
#pragma unroll
            for (int fn = 0; fn < 4; ++fn) {
                int grow = wn * 64 + fn * 16 + (lane & 15);
                int c = kh * 4 + (lane >> 4);
                int slot = c ^ (grow & 7);
                bfrag[fn] = *(const f16x8*)&Bs[buf][grow * 64 + slot * 8];
            }
#pragma unroll
            for (int fm = 0; fm < 4; ++fm) {
                float sval = s_lds[buf][kh][wm * 64 + fm * 16 + (lane & 15)];
                union { f16x8 v; __half2 h2[4]; } af;
#pragma unroll
                for (int j2 = 0; j2 < 4; ++j2) {
                    float t0 = fmaf(sval, w8[2 * j2], b8[2 * j2]);
                    float t1 = fmaf(sval, w8[2 * j2 + 1], b8[2 * j2 + 1]);
                    t0 = t0 > 0.f ? t0 : 0.f;
                    t1 = t1 > 0.f ? t1 : 0.f;
                    af.h2[j2] = __floats2half2_rn(t0, t1);
                }
#pragma unroll
                for (int fn = 0; fn < 4; ++fn) {
                    acc[fm][fn] =
                        __builtin_amdgcn_mfma_f32_16x16x32_f16(af.v, bfrag[fn], acc[fm][fn], 0, 0, 0);
                }
            }
        }
    };

    stageB(0, step0);
    __syncthreads();
    for (int t = 0; t < nst; ++t) {
        if (t + 1 < nst) stageB((t + 1) & 1, step0 + t + 1);
        compute(t & 1);
        __syncthreads();
    }

    float* Gks = G2 + (size_t)ks * BS * GG;
#pragma unroll
    for (int fm = 0; fm < 4; ++fm) {
#pragma unroll
        for (int fn = 0; fn < 4; ++fn) {
            int bs = bs0 + wm * 64 + fm * 16 + ((lane >> 4) << 2);
            int g = g0 + wn * 64 + fn * 16 + (lane & 15);
            float* base = Gks + (size_t)bs * GG + g;
#pragma unroll
            for (int r = 0; r < 4; ++r) base[r * GG] = acc[fm][fn][r];
        }
    }
}

// ---------------- reduce K-split partials + biases -> Xg3[t][g][b] ----------------
__global__ __launch_bounds__(256) void k_reduce_t(const float* __restrict__ G2,
                                                  const float* __restrict__ b_ih,
                                                  const float* __restrict__ b_hh,
                                                  float* __restrict__ Xg3) {
    __shared__ float ld[4 * 128 * 17];  // [t][g][b] pad 17
    int tid = threadIdx.x;
    int t0 = blockIdx.x * 4;   // 16
    int g0 = blockIdx.y * 128; // 4
    // phase 1: sum partials; slots (b, t, g4)
#pragma unroll
    for (int i = 0; i < 8; ++i) {
        int s2 = i * 256 + tid;
        int b = s2 >> 7;
        int t = (s2 >> 5) & 3;
        int g4 = s2 & 31;
        size_t base = (size_t)(b * 64 + t0 + t) * GG + g0 + g4 * 4;
        float4 a = {0.f, 0.f, 0.f, 0.f};
#pragma unroll
        for (int p = 0; p < KS; ++p) {
            float4 v = *(const float4*)&G2[(size_t)p * BS * GG + base];
            a.x += v.x; a.y += v.y; a.z += v.z; a.w += v.w;
        }
        int lb = (t * 128 + g4 * 4) * 17 + b;
        ld[lb] = a.x; ld[lb + 17] = a.y; ld[lb + 34] = a.z; ld[lb + 51] = a.w;
    }
    __syncthreads();
    // phase 2: transposed write; slots (t, g, b4)
#pragma unroll
    for (int i = 0; i < 8; ++i) {
        int s2 = i * 256 + tid;
        int t = s2 >> 9;
        int g = (s2 >> 2) & 127;
        int b4 = s2 & 3;
        float bias = b_ih[g0 + g] + b_hh[g0 + g];
        int lb = (t * 128 + g) * 17 + b4 * 4;
        float4 v = {ld[lb] + bias, ld[lb + 1] + bias, ld[lb + 2] + bias, ld[lb + 3] + bias};
        *(float4*)&Xg3[(size_t)((t0 + t) * GG + g0 + g) * 16 + b4 * 4] = v;
    }
}

// ---------------- LSTM via MFMA: 1 block, 8 waves, all 16 batches ----------------
// Per step: gates[16b][512g] = h[16b][128] @ Whh[512][128]^T  (fp16 MFMA, fp32 acc)
// Wave w owns gate-tiles {w, w+8, w+16, w+24}: each lane holds i,f,g,o for
// (batch m=lhi*4+r, hdim d=w*16+l15) in its 4 C-frags; c stays in registers.
// Whh frags (64 VGPR) resident all 64 steps; Xg3 reads coalesced float4.
__global__ __launch_bounds__(512, 2) void k_lstm_mfma(const float* __restrict__ Xg3,
                                                      const _Float16* __restrict__ whh_h,
                                                      const float* __restrict__ head_w,
                                                      const float* __restrict__ head_b,
                                                      float* __restrict__ out) {
    __shared__ __align__(16) _Float16 h_f16[16 * 136];  // [m][d] stride 136
    __shared__ __align__(16) float hf[16][132];         // final h fp32 for head

    int tid = threadIdx.x;
    int lane = tid & 63;
    int w = tid >> 6;        // 0..7
    int l15 = lane & 15;
    int lhi = lane >> 4;     // 0..3
    int mbase = lhi * 4;     // C rows (batch) for this lane
    int d = w * 16 + l15;    // hdim owned by this lane

    // Whh B-fragments resident in VGPRs: lane holds Whh[g=q*128+d][ks2*32+lhi*8+0..7]
    f16x8 wfh[4][4];
#pragma unroll
    for (int q = 0; q < 4; ++q) {
        int g = q * 128 + d;
#pragma unroll
        for (int ks2 = 0; ks2 < 4; ++ks2)
            wfh[q][ks2] = *(const f16x8*)&whh_h[g * HH + ks2 * 32 + lhi * 8];
    }
    for (int i = tid; i < 16 * 136; i += 512) h_f16[i] = (_Float16)0.f;
    float c4[4] = {0.f, 0.f, 0.f, 0.f};
    __syncthreads();

    // xg[q] = Xg3[t][g=q*128+d][mbase..mbase+3]  (coalesced float4/lane)
    float4 xg[4];
#pragma unroll
    for (int q = 0; q < 4; ++q)
        xg[q] = *(const float4*)&Xg3[(size_t)(q * 128 + d) * 16 + mbase];

    for (int t = 0; t < SS; ++t) {
        // A-frags from LDS h
        f16x8 ah[4];
#pragma unroll
        for (int ks2 = 0; ks2 < 4; ++ks2)
            ah[ks2] = *(const f16x8*)&h_f16[l15 * 136 + ks2 * 32 + lhi * 8];
        f32x4 acc[4] = {};
#pragma unroll
        for (int ks2 = 0; ks2 < 4; ++ks2) {
#pragma unroll
            for (int q = 0; q < 4; ++q)
                acc[q] = __builtin_amdgcn_mfma_f32_16x16x32_f16(ah[ks2], wfh[q][ks2], acc[q], 0, 0, 0);
        }
        __syncthreads();  // all h reads done before overwrite
#pragma unroll
        for (int r = 0; r < 4; ++r) {
            float ig = acc[0][r] + ((const float*)&xg[0])[r];
            float fg = acc[1][r] + ((const float*)&xg[1])[r];
            float gg = acc[2][r] + ((const float*)&xg[2])[r];
            float og = acc[3][r] + ((const float*)&xg[3])[r];
            float si = fast_sigmoid(ig);
            float sf = fast_sigmoid(fg);
            float so = fast_sigmoid(og);
            c4[r] = sf * c4[r] + si * fast_tanh(gg);
            float h = so * fast_tanh(c4[r]);
            int m = mbase + r;
            h_f16[m * 136 + d] = (_Float16)h;
            if (t == SS - 1) hf[m][d] = h;
        }
        // prefetch next step's Xg slice (in flight across barrier + next MFMA phase)
        int tn = (t + 1) & 63;
#pragma unroll
        for (int q = 0; q < 4; ++q)
            xg[q] = *(const float4*)&Xg3[((size_t)tn * GG + q * 128 + d) * 16 + mbase];
        __syncthreads();  // new h visible
    }

    // fused head: out[b][n] = head_b[n] + sum_d hf[b][d]*head_w[n][d]
    if (tid < NN) {
        float4 wr4[32];
        const float4* w4 = (const float4*)&head_w[tid * HH];
#pragma unroll
        for (int j4 = 0; j4 < 32; ++j4) wr4[j4] = w4[j4];
        float hb = head_b[tid];
        for (int b = 0; b < NB; ++b) {
            const float4* h4 = (const float4*)&hf[b][0];
            float a0 = 0.f, a1 = 0.f, a2 = 0.f, a3 = 0.f;
#pragma unroll
            for (int j4 = 0; j4 < 32; ++j4) {
                float4 hv = h4[j4];
                float4 wv = wr4[j4];
                a0 = fmaf(wv.x, hv.x, a0);
                a1 = fmaf(wv.y, hv.y, a1);
                a2 = fmaf(wv.z, hv.z, a2);
                a3 = fmaf(wv.w, hv.w, a3);
            }
            out[b * NN + tid] = hb + (a0 + a1) + (a2 + a3);
        }
    }
}

// ---------------- launch ----------------
extern "C" void kernel_launch(void* const* d_in, const int* in_sizes, int n_in, void* d_out,
                              int out_size, void* d_ws, size_t ws_size, hipStream_t stream) {
    const float* x = (const float*)d_in[0];
    const int* ei = (const int*)d_in[1];  // integer inputs arrive as int32
    const float* gat_w = (const float*)d_in[2];
    const float* a_src = (const float*)d_in[3];
    const float* a_dst = (const float*)d_in[4];
    const float* gat_b = (const float*)d_in[5];
    const float* w_ih = (const float*)d_in[6];
    const float* w_hh = (const float*)d_in[7];
    const float* b_ih = (const float*)d_in[8];
    const float* b_hh = (const float*)d_in[9];
    const float* head_w = (const float*)d_in[10];
    const float* head_b = (const float*)d_in[11];
    float* out = (float*)d_out;

    char* ws = (char*)d_ws;
    float* xt = (float*)(ws + 0);                      // 2,048,000 (dead after k_gat)
    float* s = (float*)(ws + 2048000u);                // 2,048,000 (dead after k_gemm)
    float* G2 = (float*)(ws + 4096000u);               // 16*1024*512*4 = 33,554,432
    _Float16* whh_h = (_Float16*)(ws + 37650432u);     // 131,072
    _Float16* w_h = (_Float16*)(ws + 37912576u);       // 16,384,000
    char* base2 = ws + 54296576u;                      // misc 65,536
    int* offsets = (int*)(base2);
    int* esrc = (int*)(base2 + 4096);
    float* scal = (float*)(base2 + 45056);
    float* Xg3 = (float*)(ws + 0);                     // 2,097,152 [t][g][b] — overlaps xt+s
                                                       // (both dead by k_reduce_t; stream-ordered)

    k_prep<<<4864, 256, 0, stream>>>(x, xt, w_hh, whh_h, w_ih, w_h);
    k_graph<<<1, 512, 0, stream>>>(ei, gat_w, a_src, a_dst, offsets, esrc, scal);
    k_gat<<<dim3(BS / 256, NN), 256, 0, stream>>>(xt, offsets, esrc, scal, s);
    k_gemm_mfma<<<dim3(8, 4, KS), 256, 0, stream>>>(w_h, s, gat_w, gat_b, G2);
    k_reduce_t<<<dim3(16, 4), 256, 0, stream>>>(G2, b_ih, b_hh, Xg3);
    k_lstm_mfma<<<1, 512, 0, stream>>>(Xg3, whh_h, head_w, head_b, out);
}

// Round 8
// 180.267 us; speedup vs baseline: 1.2058x; 1.0018x over previous
//
#include <hip/hip_runtime.h>
#include <hip/hip_bf16.h>
#include <hip/hip_fp16.h>

// ---------------- problem constants ----------------
constexpr int NB = 16;       // batch
constexpr int SS = 64;       // seq len
constexpr int BS = 1024;     // NB*SS
constexpr int NN = 500;      // nodes
constexpr int FF = 32;       // gat out features
constexpr int EE = 8000;     // edges (without self loops)
constexpr int ET = 8500;     // edges + self loops
constexpr int KK = 16000;    // NN*FF  (lstm input size)
constexpr int HH = 128;      // lstm hidden
constexpr int GG = 512;      // 4*HH
constexpr int KS = 16;       // K-split for the big GEMM (250 steps of 64k)

typedef __attribute__((ext_vector_type(8))) _Float16 f16x8;
typedef __attribute__((ext_vector_type(4))) float f32x4;

__device__ __forceinline__ void gload_lds16(const void* g, void* l) {
    __builtin_amdgcn_global_load_lds((const __attribute__((address_space(1))) void*)g,
                                     (__attribute__((address_space(3))) void*)l, 16, 0, 0);
}

__device__ __forceinline__ float fast_sigmoid(float x) {
    return __builtin_amdgcn_rcpf(1.f + __expf(-x));
}

// ---------------- fused prep: transpose_x | whh->fp16 | w_ih->fp16 swizzled ----------------
__global__ __launch_bounds__(256) void k_prep(const float* __restrict__ x, float* __restrict__ xt,
                                              const float* __restrict__ whh,
                                              _Float16* __restrict__ whh_h,
                                              const float* __restrict__ w_ih,
                                              _Float16* __restrict__ w_h) {
    __shared__ float tile[32][33];
    int bid = blockIdx.x;
    int tid = threadIdx.x;
    if (bid < 512) {
        // xt[n][bs] = x[bs][n]
        int n0 = (bid & 15) * 32, bs0 = (bid >> 4) * 32;
        int tx = tid & 31, ty = tid >> 5;  // 32 x 8
#pragma unroll
        for (int i = 0; i < 4; ++i) {
            int n = n0 + tx, bs = bs0 + ty + i * 8;
            tile[ty + i * 8][tx] = (n < NN) ? x[bs * NN + n] : 0.f;
        }
        __syncthreads();
#pragma unroll
        for (int i = 0; i < 4; ++i) {
            int n = n0 + ty + i * 8, bs = bs0 + tx;
            if (n < NN) xt[n * BS + bs] = tile[tx][ty + i * 8];
        }
    } else if (bid < 768) {
        // whh [512][128] fp32 -> fp16 (same layout)
        int idx = (bid - 512) * 256 + tid;  // 65536
        whh_h[idx] = (_Float16)whh[idx];
    } else {
        // w_h[g][blk*64 + sl*8 + j] = (fp16) w_ih[g][blk*64 + (sl^(g&7))*8 + j]
        int r = bid - 768;            // 0..4095
        int g = r >> 3;               // 512 rows
        int id = (r & 7) * 256 + tid; // 0..2047, 2000 used
        if (id < 2000) {
            int blk = id >> 3, sl = id & 7;
            int srcc = sl ^ (g & 7);
            const float* src = w_ih + (size_t)g * KK + blk * 64 + srcc * 8;
            float4 v0 = *(const float4*)src;
            float4 v1 = *(const float4*)(src + 4);
            union { __half2 h2[4]; uint4 q; } u;
            u.h2[0] = __floats2half2_rn(v0.x, v0.y);
            u.h2[1] = __floats2half2_rn(v0.z, v0.w);
            u.h2[2] = __floats2half2_rn(v1.x, v1.y);
            u.h2[3] = __floats2half2_rn(v1.z, v1.w);
            *(uint4*)(w_h + (size_t)g * KK + blk * 64 + sl * 8) = u.q;
        }
    }
}

// ---------------- fused graph build: count -> scan -> scatter (1 block) ----------------
__global__ __launch_bounds__(512) void k_graph(const int* __restrict__ ei,
                                               const float* __restrict__ gat_w,
                                               const float* __restrict__ a_src,
                                               const float* __restrict__ a_dst,
                                               int* __restrict__ offsets,
                                               int* __restrict__ esrc,
                                               float* __restrict__ scal) {
    __shared__ int cnt[512];
    __shared__ int sc[2][512];
    __shared__ int cur[512];
    int t = threadIdx.x;  // 512
    cnt[t] = 0;
    __syncthreads();
    for (int e = t; e < ET; e += 512) {
        int d = (e < EE) ? ei[EE + e] : (e - EE);
        atomicAdd(&cnt[d], 1);
    }
    __syncthreads();
    sc[0][t] = cnt[t];
    __syncthreads();
    int pb = 0;
    for (int off = 1; off < 512; off <<= 1) {
        int v = sc[pb][t];
        if (t >= off) v += sc[pb][t - off];
        sc[pb ^ 1][t] = v;
        pb ^= 1;
        __syncthreads();
    }
    int excl = sc[pb][t] - cnt[t];
    if (t <= NN) offsets[t] = excl;
    cur[t] = excl;
    if (t == 0) {
        float ws = 0.f, wd = 0.f;
        for (int f = 0; f < FF; ++f) {
            ws += gat_w[f] * a_src[f];
            wd += gat_w[f] * a_dst[f];
        }
        scal[0] = ws;
        scal[1] = wd;
    }
    __syncthreads();
    for (int e = t; e < ET; e += 512) {
        int sidx = (e < EE) ? ei[e] : (e - EE);
        int d = (e < EE) ? ei[EE + e] : (e - EE);
        int pos = atomicAdd(&cur[d], 1);
        esrc[pos] = sidx;
    }
}

// ---------------- GAT: per-(n,bs) edge softmax -> s[n][bs] ----------------
__global__ void k_gat(const float* __restrict__ xt, const int* __restrict__ offsets,
                      const int* __restrict__ esrc, const float* __restrict__ scal,
                      float* __restrict__ s) {
    int n = blockIdx.y;
    int bs = blockIdx.x * 256 + threadIdx.x;
    float ws = scal[0], wd = scal[1];
    float xd = xt[n * BS + bs];
    float wdxd = wd * xd;
    int e0 = offsets[n], e1 = offsets[n + 1];
    float m = -1e30f, den = 0.f, num = 0.f;
    for (int j = e0; j < e1; ++j) {
        int sidx = esrc[j];  // uniform across wave
        float xs = xt[sidx * BS + bs];
        float z = ws * xs + wdxd;
        float l = (z > 0.f) ? z : 0.2f * z;  // leaky_relu 0.2
        if (l > m) {
            float r = __expf(m - l);
            den *= r;
            num *= r;
            m = l;
        }
        float p = __expf(l - m);
        den += p;
        num += p * xs;
    }
    s[n * BS + bs] = num / den;
}

// ---------------- big GEMM via fp16 MFMA ----------------
__global__ __launch_bounds__(256, 2) void k_gemm_mfma(
    const _Float16* __restrict__ w_h, const float* __restrict__ s,
    const float* __restrict__ gat_w, const float* __restrict__ gat_b,
    float* __restrict__ G2) {
    __shared__ __align__(16) _Float16 Bs[2][128 * 64];  // [buf][g][k] swizzled image
    __shared__ float s_lds[2][2][128];                  // [buf][node][bs_local]

    int tid = threadIdx.x;
    int lane = tid & 63;
    int w = tid >> 6;
    int wm = w >> 1, wn = w & 1;
    int bm = blockIdx.x, bn = blockIdx.y, ks = blockIdx.z;
    int bs0 = bm * 128, g0 = bn * 128;
    int step0 = (ks * 250) >> 4;
    int nst = (((ks + 1) * 250) >> 4) - step0;  // 15 or 16

    int fbase = (lane >> 4) * 8;
    float w8[8], b8[8];
#pragma unroll
    for (int j = 0; j < 8; ++j) {
        w8[j] = gat_w[fbase + j];
        b8[j] = gat_b[fbase + j];
    }

    f32x4 acc[4][4] = {};

    auto stageB = [&](int buf, int stepg) {
#pragma unroll
        for (int qq = 0; qq < 4; ++qq) {
            int q = w * 4 + qq;
            int row_local = q * 8 + (lane >> 3);
            int sl = lane & 7;
            const _Float16* srcp = w_h + (size_t)(g0 + row_local) * KK + stepg * 64 + sl * 8;
            gload_lds16(srcp, &Bs[buf][q * 512]);
        }
        int row = tid >> 7, col = tid & 127;
        int n = 2 * stepg + row;
        s_lds[buf][row][col] = s[n * BS + bs0 + col];
    };

    auto compute = [&](int buf) {
#pragma unroll
        for (int kh = 0; kh < 2; ++kh) {
            f16x8 bfrag[4];
#pragma unroll
            for (int fn = 0; fn < 4; ++fn) {
                int grow = wn * 64 + fn * 16 + (lane & 15);
                int c = kh * 4 + (lane >> 4);
                int slot = c ^ (grow & 7);
                bfrag[fn] = *(const f16x8*)&Bs[buf][grow * 64 + slot * 8];
            }
#pragma unroll
            for (int fm = 0; fm < 4; ++fm) {
                float sval = s_lds[buf][kh][wm * 64 + fm * 16 + (lane & 15)];
                union { f16x8 v; __half2 h2[4]; } af;
#pragma unroll
                for (int j2 = 0; j2 < 4; ++j2) {
                    float t0 = fmaf(sval, w8[2 * j2], b8[2 * j2]);
                    float t1 = fmaf(sval, w8[2 * j2 + 1], b8[2 * j2 + 1]);
                    t0 = t0 > 0.f ? t0 : 0.f;
                    t1 = t1 > 0.f ? t1 : 0.f;
                    af.h2[j2] = __floats2half2_rn(t0, t1);
                }
#pragma unroll
                for (int fn = 0; fn < 4; ++fn) {
                    acc[fm][fn] =
                        __builtin_amdgcn_mfma_f32_16x16x32_f16(af.v, bfrag[fn], acc[fm][fn], 0, 0, 0);
                }
            }
        }
    };

    stageB(0, step0);
    __syncthreads();
    for (int t = 0; t < nst; ++t) {
        if (t + 1 < nst) stageB((t + 1) & 1, step0 + t + 1);
        compute(t & 1);
        __syncthreads();
    }

    float* Gks = G2 + (size_t)ks * BS * GG;
#pragma unroll
    for (int fm = 0; fm < 4; ++fm) {
#pragma unroll
        for (int fn = 0; fn < 4; ++fn) {
            int bs = bs0 + wm * 64 + fm * 16 + ((lane >> 4) << 2);
            int g = g0 + wn * 64 + fn * 16 + (lane & 15);
            float* base = Gks + (size_t)bs * GG + g;
#pragma unroll
            for (int r = 0; r < 4; ++r) base[r * GG] = acc[fm][fn][r];
        }
    }
}

// ---------------- reduce K-split partials + biases -> Xg3[t][g][b] ----------------
__global__ __launch_bounds__(256) void k_reduce_t(const float* __restrict__ G2,
                                                  const float* __restrict__ b_ih,
                                                  const float* __restrict__ b_hh,
                                                  float* __restrict__ Xg3) {
    __shared__ float ld[4 * 128 * 17];  // [t][g][b] pad 17
    int tid = threadIdx.x;
    int t0 = blockIdx.x * 4;   // 16
    int g0 = blockIdx.y * 128; // 4
    // phase 1: sum partials; slots (b, t, g4)
#pragma unroll
    for (int i = 0; i < 8; ++i) {
        int s2 = i * 256 + tid;
        int b = s2 >> 7;
        int t = (s2 >> 5) & 3;
        int g4 = s2 & 31;
        size_t base = (size_t)(b * 64 + t0 + t) * GG + g0 + g4 * 4;
        float4 a = {0.f, 0.f, 0.f, 0.f};
#pragma unroll
        for (int p = 0; p < KS; ++p) {
            float4 v = *(const float4*)&G2[(size_t)p * BS * GG + base];
            a.x += v.x; a.y += v.y; a.z += v.z; a.w += v.w;
        }
        int lb = (t * 128 + g4 * 4) * 17 + b;
        ld[lb] = a.x; ld[lb + 17] = a.y; ld[lb + 34] = a.z; ld[lb + 51] = a.w;
    }
    __syncthreads();
    // phase 2: transposed write; slots (t, g, b4)
#pragma unroll
    for (int i = 0; i < 8; ++i) {
        int s2 = i * 256 + tid;
        int t = s2 >> 9;
        int g = (s2 >> 2) & 127;
        int b4 = s2 & 3;
        float bias = b_ih[g0 + g] + b_hh[g0 + g];
        int lb = (t * 128 + g) * 17 + b4 * 4;
        float4 v = {ld[lb] + bias, ld[lb + 1] + bias, ld[lb + 2] + bias, ld[lb + 3] + bias};
        *(float4*)&Xg3[(size_t)((t0 + t) * GG + g0 + g) * 16 + b4 * 4] = v;
    }
}

// ---------------- LSTM via MFMA: 1 block, 8 waves, all 16 batches ----------------
// gates[16b][512g] = h[16b][128] @ Whh[512][128]^T per step (fp16 MFMA, fp32 acc).
// Wave w owns gate-tiles {w,w+8,w+16,w+24}: lane holds i,f,g,o for (m=lhi*4+r,
// d=w*16+l15). Whh frags resident in VGPRs (launch_bounds(512,1) -> no 128 cap).
// Double-buffered h + raw s_barrier (no vmcnt drain) -> Xg prefetch stays in flight.
__global__ __launch_bounds__(512, 1) void k_lstm_mfma(const float* __restrict__ Xg3,
                                                      const _Float16* __restrict__ whh_h,
                                                      const float* __restrict__ head_w,
                                                      const float* __restrict__ head_b,
                                                      float* __restrict__ out) {
    __shared__ __align__(16) _Float16 h0[16 * 136];  // [m][d] stride 136
    __shared__ __align__(16) _Float16 h1[16 * 136];
    __shared__ __align__(16) float hf[16][132];      // final h fp32 for head

    int tid = threadIdx.x;
    int lane = tid & 63;
    int w = tid >> 6;        // 0..7
    int l15 = lane & 15;
    int lhi = lane >> 4;     // 0..3
    int mbase = lhi * 4;     // C rows (batch) for this lane
    int d = w * 16 + l15;    // hdim owned by this lane

    // Whh B-fragments resident in VGPRs: lane holds Whh[g=q*128+d][ks2*32+lhi*8+0..7]
    f16x8 wfh[4][4];
#pragma unroll
    for (int q = 0; q < 4; ++q) {
        int g = q * 128 + d;
#pragma unroll
        for (int ks2 = 0; ks2 < 4; ++ks2)
            wfh[q][ks2] = *(const f16x8*)&whh_h[g * HH + ks2 * 32 + lhi * 8];
    }
    for (int i = tid; i < 16 * 136; i += 512) h0[i] = (_Float16)0.f;
    float c4[4] = {0.f, 0.f, 0.f, 0.f};

    // 2-step-deep Xg prefetch in registers
    float4 xgA[4], xgB[4];
#pragma unroll
    for (int q = 0; q < 4; ++q) {
        xgA[q] = *(const float4*)&Xg3[(size_t)(0 * GG + q * 128 + d) * 16 + mbase];
        xgB[q] = *(const float4*)&Xg3[(size_t)(1 * GG + q * 128 + d) * 16 + mbase];
    }
    __syncthreads();  // one-time full drain; h0 zeroed + wfh/xg loads done

    auto lstm_step = [&](const _Float16* hr, _Float16* hw, float4 (&xg)[4], int t) {
        f16x8 ah[4];
#pragma unroll
        for (int ks2 = 0; ks2 < 4; ++ks2)
            ah[ks2] = *(const f16x8*)&hr[l15 * 136 + ks2 * 32 + lhi * 8];
        f32x4 acc[4] = {};
#pragma unroll
        for (int ks2 = 0; ks2 < 4; ++ks2) {
#pragma unroll
            for (int q = 0; q < 4; ++q)
                acc[q] = __builtin_amdgcn_mfma_f32_16x16x32_f16(ah[ks2], wfh[q][ks2], acc[q], 0, 0, 0);
        }
        // gate sums (consume xg)
        float ig[4], fg[4], gg[4], og[4];
#pragma unroll
        for (int r = 0; r < 4; ++r) {
            ig[r] = acc[0][r] + ((const float*)&xg[0])[r];
            fg[r] = acc[1][r] + ((const float*)&xg[1])[r];
            gg[r] = acc[2][r] + ((const float*)&xg[2])[r];
            og[r] = acc[3][r] + ((const float*)&xg[3])[r];
        }
        // prefetch xg for t+2 (wrapped read at tail: harmless, values unused)
        int tn = (t + 2) & 63;
#pragma unroll
        for (int q = 0; q < 4; ++q)
            xg[q] = *(const float4*)&Xg3[((size_t)tn * GG + q * 128 + d) * 16 + mbase];
        // nonlinearity: c = sig(f)c + sig(i)tanh(g); h = sig(o)tanh(c)
        // sig(a)*tanh(b) = sign(b)*(1-w)*rcp((1+u)(1+w)), u=e^-a, w=e^-2|b| (one rcp)
#pragma unroll
        for (int r = 0; r < 4; ++r) {
            float sf = fast_sigmoid(fg[r]);
            float u = __expf(-ig[r]);
            float wv = __expf(-2.f * fabsf(gg[r]));
            float st = copysignf((1.f - wv) * __builtin_amdgcn_rcpf((1.f + u) * (1.f + wv)), gg[r]);
            c4[r] = sf * c4[r] + st;
            float u2 = __expf(-og[r]);
            float w2 = __expf(-2.f * fabsf(c4[r]));
            float h = copysignf((1.f - w2) * __builtin_amdgcn_rcpf((1.f + u2) * (1.f + w2)), c4[r]);
            int m = mbase + r;
            hw[m * 136 + d] = (_Float16)h;
            if (t == SS - 1) hf[m][d] = h;
        }
        // raw barrier: drain LDS only (ds_writes visible), keep global loads in flight
        asm volatile("s_waitcnt lgkmcnt(0)" ::: "memory");
        __builtin_amdgcn_s_barrier();
        asm volatile("" ::: "memory");
    };

    for (int tt = 0; tt < SS; tt += 2) {
        lstm_step(h0, h1, xgA, tt);
        lstm_step(h1, h0, xgB, tt + 1);
    }

    // fused head: out[b][n] = head_b[n] + sum_d hf[b][d]*head_w[n][d]
    if (tid < NN) {
        float4 wr4[32];
        const float4* w4 = (const float4*)&head_w[tid * HH];
#pragma unroll
        for (int j4 = 0; j4 < 32; ++j4) wr4[j4] = w4[j4];
        float hb = head_b[tid];
        for (int b = 0; b < NB; ++b) {
            const float4* h4 = (const float4*)&hf[b][0];
            float a0 = 0.f, a1 = 0.f, a2 = 0.f, a3 = 0.f;
#pragma unroll
            for (int j4 = 0; j4 < 32; ++j4) {
                float4 hv = h4[j4];
                float4 wv = wr4[j4];
                a0 = fmaf(wv.x, hv.x, a0);
                a1 = fmaf(wv.y, hv.y, a1);
                a2 = fmaf(wv.z, hv.z, a2);
                a3 = fmaf(wv.w, hv.w, a3);
            }
            out[b * NN + tid] = hb + (a0 + a1) + (a2 + a3);
        }
    }
}

// ---------------- launch ----------------
extern "C" void kernel_launch(void* const* d_in, const int* in_sizes, int n_in, void* d_out,
                              int out_size, void* d_ws, size_t ws_size, hipStream_t stream) {
    const float* x = (const float*)d_in[0];
    const int* ei = (const int*)d_in[1];  // integer inputs arrive as int32
    const float* gat_w = (const float*)d_in[2];
    const float* a_src = (const float*)d_in[3];
    const float* a_dst = (const float*)d_in[4];
    const float* gat_b = (const float*)d_in[5];
    const float* w_ih = (const float*)d_in[6];
    const float* w_hh = (const float*)d_in[7];
    const float* b_ih = (const float*)d_in[8];
    const float* b_hh = (const float*)d_in[9];
    const float* head_w = (const float*)d_in[10];
    const float* head_b = (const float*)d_in[11];
    float* out = (float*)d_out;

    char* ws = (char*)d_ws;
    float* xt = (float*)(ws + 0);                      // 2,048,000 (dead after k_gat)
    float* s = (float*)(ws + 2048000u);                // 2,048,000 (dead after k_gemm)
    float* G2 = (float*)(ws + 4096000u);               // 16*1024*512*4 = 33,554,432
    _Float16* whh_h = (_Float16*)(ws + 37650432u);     // 131,072
    _Float16* w_h = (_Float16*)(ws + 37912576u);       // 16,384,000
    char* base2 = ws + 54296576u;                      // misc 65,536
    int* offsets = (int*)(base2);
    int* esrc = (int*)(base2 + 4096);
    float* scal = (float*)(base2 + 45056);
    float* Xg3 = (float*)(ws + 0);                     // 2,097,152 [t][g][b] — overlaps xt+s
                                                       // (both dead by k_reduce_t; stream-ordered)

    k_prep<<<4864, 256, 0, stream>>>(x, xt, w_hh, whh_h, w_ih, w_h);
    k_graph<<<1, 512, 0, stream>>>(ei, gat_w, a_src, a_dst, offsets, esrc, scal);
    k_gat<<<dim3(BS / 256, NN), 256, 0, stream>>>(xt, offsets, esrc, scal, s);
    k_gemm_mfma<<<dim3(8, 4, KS), 256, 0, stream>>>(w_h, s, gat_w, gat_b, G2);
    k_reduce_t<<<dim3(16, 4), 256, 0, stream>>>(G2, b_ih, b_hh, Xg3);
    k_lstm_mfma<<<1, 512, 0, stream>>>(Xg3, whh_h, head_w, head_b, out);
}

// Round 9
// 178.140 us; speedup vs baseline: 1.2201x; 1.0119x over previous
//
#include <hip/hip_runtime.h>
#include <hip/hip_bf16.h>
#include <hip/hip_fp16.h>

// ---------------- problem constants ----------------
constexpr int NB = 16;       // batch
constexpr int SS = 64;       // seq len
constexpr int BS = 1024;     // NB*SS
constexpr int NN = 500;      // nodes
constexpr int FF = 32;       // gat out features
constexpr int EE = 8000;     // edges (without self loops)
constexpr int ET = 8500;     // edges + self loops
constexpr int KK = 16000;    // NN*FF  (lstm input size)
constexpr int HH = 128;      // lstm hidden
constexpr int GG = 512;      // 4*HH
constexpr int KS = 16;       // K-split for the big GEMM (250 steps of 64k)

typedef __attribute__((ext_vector_type(8))) _Float16 f16x8;
typedef __attribute__((ext_vector_type(4))) float f32x4;

__device__ __forceinline__ void gload_lds16(const void* g, void* l) {
    __builtin_amdgcn_global_load_lds((const __attribute__((address_space(1))) void*)g,
                                     (__attribute__((address_space(3))) void*)l, 16, 0, 0);
}

__device__ __forceinline__ float fast_sigmoid(float x) {
    return __builtin_amdgcn_rcpf(1.f + __expf(-x));
}

// LDS-only barrier: NO memory clobber anywhere -> no vmcnt(0) drain, global
// prefetches stay in flight across the barrier (guide §5 template / rule #18).
__device__ __forceinline__ void lds_barrier() {
    __builtin_amdgcn_sched_barrier(0);
    asm volatile("s_waitcnt lgkmcnt(0)");
    __builtin_amdgcn_sched_barrier(0);
    __builtin_amdgcn_s_barrier();
    __builtin_amdgcn_sched_barrier(0);
}

// ---------------- fused prep: transpose_x | whh->fp16 | w_ih->fp16 swizzled ----------------
__global__ __launch_bounds__(256) void k_prep(const float* __restrict__ x, float* __restrict__ xt,
                                              const float* __restrict__ whh,
                                              _Float16* __restrict__ whh_h,
                                              const float* __restrict__ w_ih,
                                              _Float16* __restrict__ w_h) {
    __shared__ float tile[32][33];
    int bid = blockIdx.x;
    int tid = threadIdx.x;
    if (bid < 512) {
        // xt[n][bs] = x[bs][n]
        int n0 = (bid & 15) * 32, bs0 = (bid >> 4) * 32;
        int tx = tid & 31, ty = tid >> 5;  // 32 x 8
#pragma unroll
        for (int i = 0; i < 4; ++i) {
            int n = n0 + tx, bs = bs0 + ty + i * 8;
            tile[ty + i * 8][tx] = (n < NN) ? x[bs * NN + n] : 0.f;
        }
        __syncthreads();
#pragma unroll
        for (int i = 0; i < 4; ++i) {
            int n = n0 + ty + i * 8, bs = bs0 + tx;
            if (n < NN) xt[n * BS + bs] = tile[tx][ty + i * 8];
        }
    } else if (bid < 768) {
        // whh [512][128] fp32 -> fp16 (same layout)
        int idx = (bid - 512) * 256 + tid;  // 65536
        whh_h[idx] = (_Float16)whh[idx];
    } else {
        // w_h[g][blk*64 + sl*8 + j] = (fp16) w_ih[g][blk*64 + (sl^(g&7))*8 + j]
        int r = bid - 768;            // 0..4095
        int g = r >> 3;               // 512 rows
        int id = (r & 7) * 256 + tid; // 0..2047, 2000 used
        if (id < 2000) {
            int blk = id >> 3, sl = id & 7;
            int srcc = sl ^ (g & 7);
            const float* src = w_ih + (size_t)g * KK + blk * 64 + srcc * 8;
            float4 v0 = *(const float4*)src;
            float4 v1 = *(const float4*)(src + 4);
            union { __half2 h2[4]; uint4 q; } u;
            u.h2[0] = __floats2half2_rn(v0.x, v0.y);
            u.h2[1] = __floats2half2_rn(v0.z, v0.w);
            u.h2[2] = __floats2half2_rn(v1.x, v1.y);
            u.h2[3] = __floats2half2_rn(v1.z, v1.w);
            *(uint4*)(w_h + (size_t)g * KK + blk * 64 + sl * 8) = u.q;
        }
    }
}

// ---------------- fused graph build: count -> scan -> scatter (1 block) ----------------
__global__ __launch_bounds__(512) void k_graph(const int* __restrict__ ei,
                                               const float* __restrict__ gat_w,
                                               const float* __restrict__ a_src,
                                               const float* __restrict__ a_dst,
                                               int* __restrict__ offsets,
                                               int* __restrict__ esrc,
                                               float* __restrict__ scal) {
    __shared__ int cnt[512];
    __shared__ int sc[2][512];
    __shared__ int cur[512];
    int t = threadIdx.x;  // 512
    cnt[t] = 0;
    __syncthreads();
    for (int e = t; e < ET; e += 512) {
        int d = (e < EE) ? ei[EE + e] : (e - EE);
        atomicAdd(&cnt[d], 1);
    }
    __syncthreads();
    sc[0][t] = cnt[t];
    __syncthreads();
    int pb = 0;
    for (int off = 1; off < 512; off <<= 1) {
        int v = sc[pb][t];
        if (t >= off) v += sc[pb][t - off];
        sc[pb ^ 1][t] = v;
        pb ^= 1;
        __syncthreads();
    }
    int excl = sc[pb][t] - cnt[t];
    if (t <= NN) offsets[t] = excl;
    cur[t] = excl;
    if (t == 0) {
        float ws = 0.f, wd = 0.f;
        for (int f = 0; f < FF; ++f) {
            ws += gat_w[f] * a_src[f];
            wd += gat_w[f] * a_dst[f];
        }
        scal[0] = ws;
        scal[1] = wd;
    }
    __syncthreads();
    for (int e = t; e < ET; e += 512) {
        int sidx = (e < EE) ? ei[e] : (e - EE);
        int d = (e < EE) ? ei[EE + e] : (e - EE);
        int pos = atomicAdd(&cur[d], 1);
        esrc[pos] = sidx;
    }
}

// ---------------- GAT: per-(n,bs) edge softmax -> s[n][bs] ----------------
__global__ void k_gat(const float* __restrict__ xt, const int* __restrict__ offsets,
                      const int* __restrict__ esrc, const float* __restrict__ scal,
                      float* __restrict__ s) {
    int n = blockIdx.y;
    int bs = blockIdx.x * 256 + threadIdx.x;
    float ws = scal[0], wd = scal[1];
    float xd = xt[n * BS + bs];
    float wdxd = wd * xd;
    int e0 = offsets[n], e1 = offsets[n + 1];
    float m = -1e30f, den = 0.f, num = 0.f;
    for (int j = e0; j < e1; ++j) {
        int sidx = esrc[j];  // uniform across wave
        float xs = xt[sidx * BS + bs];
        float z = ws * xs + wdxd;
        float l = (z > 0.f) ? z : 0.2f * z;  // leaky_relu 0.2
        if (l > m) {
            float r = __expf(m - l);
            den *= r;
            num *= r;
            m = l;
        }
        float p = __expf(l - m);
        den += p;
        num += p * xs;
    }
    s[n * BS + bs] = num / den;
}

// ---------------- big GEMM via fp16 MFMA ----------------
__global__ __launch_bounds__(256, 2) void k_gemm_mfma(
    const _Float16* __restrict__ w_h, const float* __restrict__ s,
    const float* __restrict__ gat_w, const float* __restrict__ gat_b,
    float* __restrict__ G2) {
    __shared__ __align__(16) _Float16 Bs[2][128 * 64];  // [buf][g][k] swizzled image
    __shared__ float s_lds[2][2][128];                  // [buf][node][bs_local]

    int tid = threadIdx.x;
    int lane = tid & 63;
    int w = tid >> 6;
    int wm = w >> 1, wn = w & 1;
    int bm = blockIdx.x, bn = blockIdx.y, ks = blockIdx.z;
    int bs0 = bm * 128, g0 = bn * 128;
    int step0 = (ks * 250) >> 4;
    int nst = (((ks + 1) * 250) >> 4) - step0;  // 15 or 16

    int fbase = (lane >> 4) * 8;
    float w8[8], b8[8];
#pragma unroll
    for (int j = 0; j < 8; ++j) {
        w8[j] = gat_w[fbase + j];
        b8[j] = gat_b[fbase + j];
    }

    f32x4 acc[4][4] = {};

    auto stageB = [&](int buf, int stepg) {
#pragma unroll
        for (int qq = 0; qq < 4; ++qq) {
            int q = w * 4 + qq;
            int row_local = q * 8 + (lane >> 3);
            int sl = lane & 7;
            const _Float16* srcp = w_h + (size_t)(g0 + row_local) * KK + stepg * 64 + sl * 8;
            gload_lds16(srcp, &Bs[buf][q * 512]);
        }
        int row = tid >> 7, col = tid & 127;
        int n = 2 * stepg + row;
        s_lds[buf][row][col] = s[n * BS + bs0 + col];
    };

    auto compute = [&](int buf) {
#pragma unroll
        for (int kh = 0; kh < 2; ++kh) {
            f16x8 bfrag[4];
#pragma unroll
            for (int fn = 0; fn < 4; ++fn) {
                int grow = wn * 64 + fn * 16 + (lane & 15);
                int c = kh * 4 + (lane >> 4);
                int slot = c ^ (grow & 7);
                bfrag[fn] = *(const f16x8*)&Bs[buf][grow * 64 + slot * 8];
            }
#pragma unroll
            for (int fm = 0; fm < 4; ++fm) {
                float sval = s_lds[buf][kh][wm * 64 + fm * 16 + (lane & 15)];
                union { f16x8 v; __half2 h2[4]; } af;
#pragma unroll
                for (int j2 = 0; j2 < 4; ++j2) {
                    float t0 = fmaf(sval, w8[2 * j2], b8[2 * j2]);
                    float t1 = fmaf(sval, w8[2 * j2 + 1], b8[2 * j2 + 1]);
                    t0 = t0 > 0.f ? t0 : 0.f;
                    t1 = t1 > 0.f ? t1 : 0.f;
                    af.h2[j2] = __floats2half2_rn(t0, t1);
                }
#pragma unroll
                for (int fn = 0; fn < 4; ++fn) {
                    acc[fm][fn] =
                        __builtin_amdgcn_mfma_f32_16x16x32_f16(af.v, bfrag[fn], acc[fm][fn], 0, 0, 0);
                }
            }
        }
    };

    stageB(0, step0);
    __syncthreads();
    for (int t = 0; t < nst; ++t) {
        if (t + 1 < nst) stageB((t + 1) & 1, step0 + t + 1);
        compute(t & 1);
        __syncthreads();
    }

    float* Gks = G2 + (size_t)ks * BS * GG;
#pragma unroll
    for (int fm = 0; fm < 4; ++fm) {
#pragma unroll
        for (int fn = 0; fn < 4; ++fn) {
            int bs = bs0 + wm * 64 + fm * 16 + ((lane >> 4) << 2);
            int g = g0 + wn * 64 + fn * 16 + (lane & 15);
            float* base = Gks + (size_t)bs * GG + g;
#pragma unroll
            for (int r = 0; r < 4; ++r) base[r * GG] = acc[fm][fn][r];
        }
    }
}

// ---------------- reduce K-split partials + biases -> Xg3[t][g][b] ----------------
__global__ __launch_bounds__(256) void k_reduce_t(const float* __restrict__ G2,
                                                  const float* __restrict__ b_ih,
                                                  const float* __restrict__ b_hh,
                                                  float* __restrict__ Xg3) {
    __shared__ float ld[4 * 128 * 17];  // [t][g][b] pad 17
    int tid = threadIdx.x;
    int t0 = blockIdx.x * 4;   // 16
    int g0 = blockIdx.y * 128; // 4
    // phase 1: sum partials; slots (b, t, g4)
#pragma unroll
    for (int i = 0; i < 8; ++i) {
        int s2 = i * 256 + tid;
        int b = s2 >> 7;
        int t = (s2 >> 5) & 3;
        int g4 = s2 & 31;
        size_t base = (size_t)(b * 64 + t0 + t) * GG + g0 + g4 * 4;
        float4 a = {0.f, 0.f, 0.f, 0.f};
#pragma unroll
        for (int p = 0; p < KS; ++p) {
            float4 v = *(const float4*)&G2[(size_t)p * BS * GG + base];
            a.x += v.x; a.y += v.y; a.z += v.z; a.w += v.w;
        }
        int lb = (t * 128 + g4 * 4) * 17 + b;
        ld[lb] = a.x; ld[lb + 17] = a.y; ld[lb + 34] = a.z; ld[lb + 51] = a.w;
    }
    __syncthreads();
    // phase 2: transposed write; slots (t, g, b4)
#pragma unroll
    for (int i = 0; i < 8; ++i) {
        int s2 = i * 256 + tid;
        int t = s2 >> 9;
        int g = (s2 >> 2) & 127;
        int b4 = s2 & 3;
        float bias = b_ih[g0 + g] + b_hh[g0 + g];
        int lb = (t * 128 + g) * 17 + b4 * 4;
        float4 v = {ld[lb] + bias, ld[lb + 1] + bias, ld[lb + 2] + bias, ld[lb + 3] + bias};
        *(float4*)&Xg3[(size_t)((t0 + t) * GG + g0 + g) * 16 + b4 * 4] = v;
    }
}

// ---------------- LSTM via MFMA: 1 block, 8 waves, all 16 batches ----------------
// gates[16b][512g] = h[16b][128] @ Whh[512][128]^T per step (fp16 MFMA, fp32 acc).
// Wave w owns gate-tiles {w,w+8,w+16,w+24}: lane holds i,f,g,o for (m=lhi*4+r,
// d=w*16+l15). Whh frags resident in VGPRs. lds_barrier() has NO memory clobber
// -> no vmcnt(0) drain -> Xg prefetch survives the barrier.
__global__ __launch_bounds__(512, 1) void k_lstm_mfma(const float* __restrict__ Xg3,
                                                      const _Float16* __restrict__ whh_h,
                                                      const float* __restrict__ head_w,
                                                      const float* __restrict__ head_b,
                                                      float* __restrict__ out) {
    __shared__ __align__(16) _Float16 h0[16 * 136];  // [m][d] stride 136
    __shared__ __align__(16) _Float16 h1[16 * 136];
    __shared__ __align__(16) float hf[16][132];      // final h fp32 for head

    int tid = threadIdx.x;
    int lane = tid & 63;
    int w = tid >> 6;        // 0..7
    int l15 = lane & 15;
    int lhi = lane >> 4;     // 0..3
    int mbase = lhi * 4;     // C rows (batch) for this lane
    int d = w * 16 + l15;    // hdim owned by this lane

    // Whh B-fragments resident in VGPRs: lane holds Whh[g=q*128+d][ks2*32+lhi*8+0..7]
    f16x8 wfh[4][4];
#pragma unroll
    for (int q = 0; q < 4; ++q) {
        int g = q * 128 + d;
#pragma unroll
        for (int ks2 = 0; ks2 < 4; ++ks2)
            wfh[q][ks2] = *(const f16x8*)&whh_h[g * HH + ks2 * 32 + lhi * 8];
    }
    for (int i = tid; i < 16 * 136; i += 512) h0[i] = (_Float16)0.f;
    float c4[4] = {0.f, 0.f, 0.f, 0.f};

    // 1-step-deep Xg prefetch in registers
    float4 xg[4];
#pragma unroll
    for (int q = 0; q < 4; ++q)
        xg[q] = *(const float4*)&Xg3[(size_t)(q * 128 + d) * 16 + mbase];
    __syncthreads();  // one-time full drain; h0 zeroed + wfh/xg loads done

    auto lstm_step = [&](const _Float16* hr, _Float16* hw, int t) {
        f16x8 ah[4];
#pragma unroll
        for (int ks2 = 0; ks2 < 4; ++ks2)
            ah[ks2] = *(const f16x8*)&hr[l15 * 136 + ks2 * 32 + lhi * 8];
        f32x4 acc[4] = {};
#pragma unroll
        for (int ks2 = 0; ks2 < 4; ++ks2) {
#pragma unroll
            for (int q = 0; q < 4; ++q)
                acc[q] = __builtin_amdgcn_mfma_f32_16x16x32_f16(ah[ks2], wfh[q][ks2], acc[q], 0, 0, 0);
        }
        // gate sums (consume xg)
        float ig[4], fg[4], gg[4], og[4];
#pragma unroll
        for (int r = 0; r < 4; ++r) {
            ig[r] = acc[0][r] + ((const float*)&xg[0])[r];
            fg[r] = acc[1][r] + ((const float*)&xg[1])[r];
            gg[r] = acc[2][r] + ((const float*)&xg[2])[r];
            og[r] = acc[3][r] + ((const float*)&xg[3])[r];
        }
        // prefetch xg for t+1 (wrapped read at tail: harmless, values unused)
        int tn = (t + 1) & 63;
#pragma unroll
        for (int q = 0; q < 4; ++q)
            xg[q] = *(const float4*)&Xg3[((size_t)tn * GG + q * 128 + d) * 16 + mbase];
        // nonlinearity: c = sig(f)c + sig(i)tanh(g); h = sig(o)tanh(c)
        // sig(a)*tanh(b) = sign(b)*(1-w)*rcp((1+u)(1+w)), u=e^-a, w=e^-2|b|
#pragma unroll
        for (int r = 0; r < 4; ++r) {
            float sf = fast_sigmoid(fg[r]);
            float u = __expf(-ig[r]);
            float wv = __expf(-2.f * fabsf(gg[r]));
            float st = copysignf((1.f - wv) * __builtin_amdgcn_rcpf((1.f + u) * (1.f + wv)), gg[r]);
            c4[r] = sf * c4[r] + st;
            float u2 = __expf(-og[r]);
            float w2 = __expf(-2.f * fabsf(c4[r]));
            float h = copysignf((1.f - w2) * __builtin_amdgcn_rcpf((1.f + u2) * (1.f + w2)), c4[r]);
            int m = mbase + r;
            hw[m * 136 + d] = (_Float16)h;
            if (t == SS - 1) hf[m][d] = h;
        }
        lds_barrier();  // drain LDS only; global xg prefetch stays in flight
    };

    for (int tt = 0; tt < SS; tt += 2) {
        lstm_step(h0, h1, tt);
        lstm_step(h1, h0, tt + 1);
    }

    // fused head: out[b][n] = head_b[n] + sum_d hf[b][d]*head_w[n][d]
    if (tid < NN) {
        float4 wr4[32];
        const float4* w4 = (const float4*)&head_w[tid * HH];
#pragma unroll
        for (int j4 = 0; j4 < 32; ++j4) wr4[j4] = w4[j4];
        float hb = head_b[tid];
        for (int b = 0; b < NB; ++b) {
            const float4* h4 = (const float4*)&hf[b][0];
            float a0 = 0.f, a1 = 0.f, a2 = 0.f, a3 = 0.f;
#pragma unroll
            for (int j4 = 0; j4 < 32; ++j4) {
                float4 hv = h4[j4];
                float4 wv = wr4[j4];
                a0 = fmaf(wv.x, hv.x, a0);
                a1 = fmaf(wv.y, hv.y, a1);
                a2 = fmaf(wv.z, hv.z, a2);
                a3 = fmaf(wv.w, hv.w, a3);
            }
            out[b * NN + tid] = hb + (a0 + a1) + (a2 + a3);
        }
    }
}

// ---------------- launch ----------------
extern "C" void kernel_launch(void* const* d_in, const int* in_sizes, int n_in, void* d_out,
                              int out_size, void* d_ws, size_t ws_size, hipStream_t stream) {
    const float* x = (const float*)d_in[0];
    const int* ei = (const int*)d_in[1];  // integer inputs arrive as int32
    const float* gat_w = (const float*)d_in[2];
    const float* a_src = (const float*)d_in[3];
    const float* a_dst = (const float*)d_in[4];
    const float* gat_b = (const float*)d_in[5];
    const float* w_ih = (const float*)d_in[6];
    const float* w_hh = (const float*)d_in[7];
    const float* b_ih = (const float*)d_in[8];
    const float* b_hh = (const float*)d_in[9];
    const float* head_w = (const float*)d_in[10];
    const float* head_b = (const float*)d_in[11];
    float* out = (float*)d_out;

    char* ws = (char*)d_ws;
    float* xt = (float*)(ws + 0);                      // 2,048,000 (dead after k_gat)
    float* s = (float*)(ws + 2048000u);                // 2,048,000 (dead after k_gemm)
    float* G2 = (float*)(ws + 4096000u);               // 16*1024*512*4 = 33,554,432
    _Float16* whh_h = (_Float16*)(ws + 37650432u);     // 131,072
    _Float16* w_h = (_Float16*)(ws + 37912576u);       // 16,384,000
    char* base2 = ws + 54296576u;                      // misc 65,536
    int* offsets = (int*)(base2);
    int* esrc = (int*)(base2 + 4096);
    float* scal = (float*)(base2 + 45056);
    float* Xg3 = (float*)(ws + 0);                     // 2,097,152 [t][g][b] — overlaps xt+s
                                                       // (both dead by k_reduce_t; stream-ordered)

    k_prep<<<4864, 256, 0, stream>>>(x, xt, w_hh, whh_h, w_ih, w_h);
    k_graph<<<1, 512, 0, stream>>>(ei, gat_w, a_src, a_dst, offsets, esrc, scal);
    k_gat<<<dim3(BS / 256, NN), 256, 0, stream>>>(xt, offsets, esrc, scal, s);
    k_gemm_mfma<<<dim3(8, 4, KS), 256, 0, stream>>>(w_h, s, gat_w, gat_b, G2);
    k_reduce_t<<<dim3(16, 4), 256, 0, stream>>>(G2, b_ih, b_hh, Xg3);
    k_lstm_mfma<<<1, 512, 0, stream>>>(Xg3, whh_h, head_w, head_b, out);
}

// Round 10
// 131.384 us; speedup vs baseline: 1.6544x; 1.3559x over previous
//
#include <hip/hip_runtime.h>
#include <hip/hip_bf16.h>
#include <hip/hip_fp16.h>

// ---------------- problem constants ----------------
constexpr int NB = 16;       // batch
constexpr int SS = 64;       // seq len
constexpr int BS = 1024;     // NB*SS
constexpr int NN = 500;      // nodes
constexpr int FF = 32;       // gat out features
constexpr int EE = 8000;     // edges (without self loops)
constexpr int ET = 8500;     // edges + self loops
constexpr int KK = 16000;    // NN*FF  (lstm input size)
constexpr int HH = 128;      // lstm hidden
constexpr int GG = 512;      // 4*HH
constexpr int KS = 16;       // K-split for the big GEMM (250 steps of 64k)

typedef __attribute__((ext_vector_type(8))) _Float16 f16x8;
typedef __attribute__((ext_vector_type(2))) _Float16 f16x2;
typedef __attribute__((ext_vector_type(4))) float f32x4;

__device__ __forceinline__ void gload_lds16(const void* g, void* l) {
    __builtin_amdgcn_global_load_lds((const __attribute__((address_space(1))) void*)g,
                                     (__attribute__((address_space(3))) void*)l, 16, 0, 0);
}

__device__ __forceinline__ float fast_sigmoid(float x) {
    return __builtin_amdgcn_rcpf(1.f + __expf(-x));
}

__device__ __forceinline__ float fdot2(f16x2 a, f16x2 b, float c) {
#if __has_builtin(__builtin_amdgcn_fdot2)
    return __builtin_amdgcn_fdot2(a, b, c, false);
#else
    return c + (float)a[0] * (float)b[0] + (float)a[1] * (float)b[1];
#endif
}

// LDS-only barrier: no memory clobber -> no vmcnt(0) drain; sched_barrier(0)
// pins ordering (guide rule #18).
__device__ __forceinline__ void lds_barrier() {
    __builtin_amdgcn_sched_barrier(0);
    asm volatile("s_waitcnt lgkmcnt(0)");
    __builtin_amdgcn_sched_barrier(0);
    __builtin_amdgcn_s_barrier();
    __builtin_amdgcn_sched_barrier(0);
}

// ---------------- fused prep: transpose_x | whh->fp16 | w_ih->fp16 swizzled ----------------
__global__ __launch_bounds__(256) void k_prep(const float* __restrict__ x, float* __restrict__ xt,
                                              const float* __restrict__ whh,
                                              _Float16* __restrict__ whh_h,
                                              const float* __restrict__ w_ih,
                                              _Float16* __restrict__ w_h) {
    __shared__ float tile[32][33];
    int bid = blockIdx.x;
    int tid = threadIdx.x;
    if (bid < 512) {
        // xt[n][bs] = x[bs][n]
        int n0 = (bid & 15) * 32, bs0 = (bid >> 4) * 32;
        int tx = tid & 31, ty = tid >> 5;  // 32 x 8
#pragma unroll
        for (int i = 0; i < 4; ++i) {
            int n = n0 + tx, bs = bs0 + ty + i * 8;
            tile[ty + i * 8][tx] = (n < NN) ? x[bs * NN + n] : 0.f;
        }
        __syncthreads();
#pragma unroll
        for (int i = 0; i < 4; ++i) {
            int n = n0 + ty + i * 8, bs = bs0 + tx;
            if (n < NN) xt[n * BS + bs] = tile[tx][ty + i * 8];
        }
    } else if (bid < 768) {
        // whh [512][128] fp32 -> fp16 (same layout)
        int idx = (bid - 512) * 256 + tid;  // 65536
        whh_h[idx] = (_Float16)whh[idx];
    } else {
        // w_h[g][blk*64 + sl*8 + j] = (fp16) w_ih[g][blk*64 + (sl^(g&7))*8 + j]
        int r = bid - 768;            // 0..4095
        int g = r >> 3;               // 512 rows
        int id = (r & 7) * 256 + tid; // 0..2047, 2000 used
        if (id < 2000) {
            int blk = id >> 3, sl = id & 7;
            int srcc = sl ^ (g & 7);
            const float* src = w_ih + (size_t)g * KK + blk * 64 + srcc * 8;
            float4 v0 = *(const float4*)src;
            float4 v1 = *(const float4*)(src + 4);
            union { __half2 h2[4]; uint4 q; } u;
            u.h2[0] = __floats2half2_rn(v0.x, v0.y);
            u.h2[1] = __floats2half2_rn(v0.z, v0.w);
            u.h2[2] = __floats2half2_rn(v1.x, v1.y);
            u.h2[3] = __floats2half2_rn(v1.z, v1.w);
            *(uint4*)(w_h + (size_t)g * KK + blk * 64 + sl * 8) = u.q;
        }
    }
}

// ---------------- fused graph build: count -> scan -> scatter (1 block) ----------------
__global__ __launch_bounds__(512) void k_graph(const int* __restrict__ ei,
                                               const float* __restrict__ gat_w,
                                               const float* __restrict__ a_src,
                                               const float* __restrict__ a_dst,
                                               int* __restrict__ offsets,
                                               int* __restrict__ esrc,
                                               float* __restrict__ scal) {
    __shared__ int cnt[512];
    __shared__ int sc[2][512];
    __shared__ int cur[512];
    int t = threadIdx.x;  // 512
    cnt[t] = 0;
    __syncthreads();
    for (int e = t; e < ET; e += 512) {
        int d = (e < EE) ? ei[EE + e] : (e - EE);
        atomicAdd(&cnt[d], 1);
    }
    __syncthreads();
    sc[0][t] = cnt[t];
    __syncthreads();
    int pb = 0;
    for (int off = 1; off < 512; off <<= 1) {
        int v = sc[pb][t];
        if (t >= off) v += sc[pb][t - off];
        sc[pb ^ 1][t] = v;
        pb ^= 1;
        __syncthreads();
    }
    int excl = sc[pb][t] - cnt[t];
    if (t <= NN) offsets[t] = excl;
    cur[t] = excl;
    if (t == 0) {
        float ws = 0.f, wd = 0.f;
        for (int f = 0; f < FF; ++f) {
            ws += gat_w[f] * a_src[f];
            wd += gat_w[f] * a_dst[f];
        }
        scal[0] = ws;
        scal[1] = wd;
    }
    __syncthreads();
    for (int e = t; e < ET; e += 512) {
        int sidx = (e < EE) ? ei[e] : (e - EE);
        int d = (e < EE) ? ei[EE + e] : (e - EE);
        int pos = atomicAdd(&cur[d], 1);
        esrc[pos] = sidx;
    }
}

// ---------------- GAT: per-(n,bs) edge softmax -> s[n][bs] ----------------
__global__ void k_gat(const float* __restrict__ xt, const int* __restrict__ offsets,
                      const int* __restrict__ esrc, const float* __restrict__ scal,
                      float* __restrict__ s) {
    int n = blockIdx.y;
    int bs = blockIdx.x * 256 + threadIdx.x;
    float ws = scal[0], wd = scal[1];
    float xd = xt[n * BS + bs];
    float wdxd = wd * xd;
    int e0 = offsets[n], e1 = offsets[n + 1];
    float m = -1e30f, den = 0.f, num = 0.f;
    for (int j = e0; j < e1; ++j) {
        int sidx = esrc[j];  // uniform across wave
        float xs = xt[sidx * BS + bs];
        float z = ws * xs + wdxd;
        float l = (z > 0.f) ? z : 0.2f * z;  // leaky_relu 0.2
        if (l > m) {
            float r = __expf(m - l);
            den *= r;
            num *= r;
            m = l;
        }
        float p = __expf(l - m);
        den += p;
        num += p * xs;
    }
    s[n * BS + bs] = num / den;
}

// ---------------- big GEMM via fp16 MFMA ----------------
__global__ __launch_bounds__(256, 2) void k_gemm_mfma(
    const _Float16* __restrict__ w_h, const float* __restrict__ s,
    const float* __restrict__ gat_w, const float* __restrict__ gat_b,
    float* __restrict__ G2) {
    __shared__ __align__(16) _Float16 Bs[2][128 * 64];  // [buf][g][k] swizzled image
    __shared__ float s_lds[2][2][128];                  // [buf][node][bs_local]

    int tid = threadIdx.x;
    int lane = tid & 63;
    int w = tid >> 6;
    int wm = w >> 1, wn = w & 1;
    int bm = blockIdx.x, bn = blockIdx.y, ks = blockIdx.z;
    int bs0 = bm * 128, g0 = bn * 128;
    int step0 = (ks * 250) >> 4;
    int nst = (((ks + 1) * 250) >> 4) - step0;  // 15 or 16

    int fbase = (lane >> 4) * 8;
    float w8[8], b8[8];
#pragma unroll
    for (int j = 0; j < 8; ++j) {
        w8[j] = gat_w[fbase + j];
        b8[j] = gat_b[fbase + j];
    }

    f32x4 acc[4][4] = {};

    auto stageB = [&](int buf, int stepg) {
#pragma unroll
        for (int qq = 0; qq < 4; ++qq) {
            int q = w * 4 + qq;
            int row_local = q * 8 + (lane >> 3);
            int sl = lane & 7;
            const _Float16* srcp = w_h + (size_t)(g0 + row_local) * KK + stepg * 64 + sl * 8;
            gload_lds16(srcp, &Bs[buf][q * 512]);
        }
        int row = tid >> 7, col = tid & 127;
        int n = 2 * stepg + row;
        s_lds[buf][row][col] = s[n * BS + bs0 + col];
    };

    auto compute = [&](int buf) {
#pragma unroll
        for (int kh = 0; kh < 2; ++kh) {
            f16x8 bfrag[4];
#pragma unroll
            for (int fn = 0; fn < 4; ++fn) {
                int grow = wn * 64 + fn * 16 + (lane & 15);
                int c = kh * 4 + (lane >> 4);
                int slot = c ^ (grow & 7);
                bfrag[fn] = *(const f16x8*)&Bs[buf][grow * 64 + slot * 8];
            }
#pragma unroll
            for (int fm = 0; fm < 4; ++fm) {
                float sval = s_lds[buf][kh][wm * 64 + fm * 16 + (lane & 15)];
                union { f16x8 v; __half2 h2[4]; } af;
#pragma unroll
                for (int j2 = 0; j2 < 4; ++j2) {
                    float t0 = fmaf(sval, w8[2 * j2], b8[2 * j2]);
                    float t1 = fmaf(sval, w8[2 * j2 + 1], b8[2 * j2 + 1]);
                    t0 = t0 > 0.f ? t0 : 0.f;
                    t1 = t1 > 0.f ? t1 : 0.f;
                    af.h2[j2] = __floats2half2_rn(t0, t1);
                }
#pragma unroll
                for (int fn = 0; fn < 4; ++fn) {
                    acc[fm][fn] =
                        __builtin_amdgcn_mfma_f32_16x16x32_f16(af.v, bfrag[fn], acc[fm][fn], 0, 0, 0);
                }
            }
        }
    };

    stageB(0, step0);
    __syncthreads();
    for (int t = 0; t < nst; ++t) {
        if (t + 1 < nst) stageB((t + 1) & 1, step0 + t + 1);
        compute(t & 1);
        __syncthreads();
    }

    float* Gks = G2 + (size_t)ks * BS * GG;
#pragma unroll
    for (int fm = 0; fm < 4; ++fm) {
#pragma unroll
        for (int fn = 0; fn < 4; ++fn) {
            int bs = bs0 + wm * 64 + fm * 16 + ((lane >> 4) << 2);
            int g = g0 + wn * 64 + fn * 16 + (lane & 15);
            float* base = Gks + (size_t)bs * GG + g;
#pragma unroll
            for (int r = 0; r < 4; ++r) base[r * GG] = acc[fm][fn][r];
        }
    }
}

// ---------------- reduce K-split partials + biases -> Xg[bs][512] ----------------
__global__ __launch_bounds__(256) void k_reduce(const float* __restrict__ G2,
                                                const float* __restrict__ b_ih,
                                                const float* __restrict__ b_hh,
                                                float* __restrict__ Xg) {
    int idx = blockIdx.x * 256 + threadIdx.x;  // 131072 float4 slots
    int e = idx * 4;
    int g = e & (GG - 1);
    float4 acc = *(const float4*)&b_ih[g];
    float4 bh = *(const float4*)&b_hh[g];
    acc.x += bh.x; acc.y += bh.y; acc.z += bh.z; acc.w += bh.w;
#pragma unroll
    for (int p = 0; p < KS; ++p) {
        float4 v = *(const float4*)&G2[(size_t)p * BS * GG + e];
        acc.x += v.x; acc.y += v.y; acc.z += v.z; acc.w += v.w;
    }
    *(float4*)&Xg[e] = acc;
}

// ---------------- LSTM via dot2: 16 blocks (1/batch), 512 thr ----------------
// Thread (d = tid&127, kc = tid>>7) owns gates {i,f,g,o} of hidden dim d over
// K-chunk [kc*32, kc*32+32). Weights: 64 VGPR fp16. h chunk reads are
// wave-uniform -> LDS broadcast (no BW). kc>0 write 4-float partials; kc==0
// reduces, applies nonlinearity (thread-local gates), writes fp16 h.
__global__ __launch_bounds__(512, 1) void k_lstm_dot2(const float* __restrict__ Xg,
                                                      const _Float16* __restrict__ whh_h,
                                                      const float* __restrict__ head_w,
                                                      const float* __restrict__ head_b,
                                                      float* __restrict__ out) {
    __shared__ __align__(16) _Float16 h_lds[HH];
    __shared__ __align__(16) float part[3 * HH * 4];
    __shared__ __align__(16) float hf[HH];

    int tid = threadIdx.x;
    int b = blockIdx.x;
    int d = tid & 127;
    int kc = tid >> 7;   // 0..3
    int k0 = kc * 32;

    union U8 { f16x8 v; f16x2 h[4]; };

    // weights: w8[q][j] = Whh[q*128+d][k0 + j*8 .. +7]  (fp16, 64 VGPRs)
    U8 w8[4][4];
#pragma unroll
    for (int q = 0; q < 4; ++q)
#pragma unroll
        for (int j = 0; j < 4; ++j)
            w8[q][j].v = *(const f16x8*)&whh_h[(q * HH + d) * HH + k0 + j * 8];

    if (tid < HH) h_lds[tid] = (_Float16)0.f;
    float c = 0.f;
    float xg[4] = {0.f, 0.f, 0.f, 0.f};
    if (kc == 0) {
#pragma unroll
        for (int q = 0; q < 4; ++q) xg[q] = Xg[(size_t)(b * SS) * GG + q * HH + d];
    }
    __syncthreads();

    for (int t = 0; t < SS; ++t) {
        // h chunk: wave-uniform addresses -> broadcast reads
        U8 hh[4];
#pragma unroll
        for (int j = 0; j < 4; ++j) hh[j].v = *(const f16x8*)&h_lds[k0 + j * 8];
        float acc[4] = {0.f, 0.f, 0.f, 0.f};
#pragma unroll
        for (int j = 0; j < 4; ++j)
#pragma unroll
            for (int p = 0; p < 4; ++p) {
#pragma unroll
                for (int q = 0; q < 4; ++q)
                    acc[q] = fdot2(hh[j].h[p], w8[q][j].h[p], acc[q]);
            }
        if (kc) {
            float4 pv = {acc[0], acc[1], acc[2], acc[3]};
            *(float4*)&part[((kc - 1) * HH + d) * 4] = pv;
        }
        lds_barrier();  // partials visible; xg global prefetch stays in flight
        if (kc == 0) {
            float4 p1 = *(const float4*)&part[(0 * HH + d) * 4];
            float4 p2 = *(const float4*)&part[(1 * HH + d) * 4];
            float4 p3 = *(const float4*)&part[(2 * HH + d) * 4];
            float ig = acc[0] + p1.x + p2.x + p3.x + xg[0];
            float fg = acc[1] + p1.y + p2.y + p3.y + xg[1];
            float gg = acc[2] + p1.z + p2.z + p3.z + xg[2];
            float og = acc[3] + p1.w + p2.w + p3.w + xg[3];
            // prefetch next step's xg (hidden under next dot2 phase)
            int tn = (t + 1) & 63;
#pragma unroll
            for (int q = 0; q < 4; ++q)
                xg[q] = Xg[(size_t)(b * SS + tn) * GG + q * HH + d];
            // c = sig(f)c + sig(i)tanh(g); h = sig(o)tanh(c)
            // sig(a)tanh(b) = sign(b)(1-w)rcp((1+u)(1+w)), u=e^-a, w=e^-2|b|
            float sf = fast_sigmoid(fg);
            float u = __expf(-ig);
            float wv = __expf(-2.f * fabsf(gg));
            float st = copysignf((1.f - wv) * __builtin_amdgcn_rcpf((1.f + u) * (1.f + wv)), gg);
            c = sf * c + st;
            float u2 = __expf(-og);
            float w2 = __expf(-2.f * fabsf(c));
            float h = copysignf((1.f - w2) * __builtin_amdgcn_rcpf((1.f + u2) * (1.f + w2)), c);
            h_lds[d] = (_Float16)h;
            if (t == SS - 1) hf[d] = h;
        }
        lds_barrier();  // new h visible
    }

    __syncthreads();
    // fused head: out[b][n] = head_b[n] + sum_d hf[d]*head_w[n][d]
    if (tid < NN) {
        float a0 = head_b[tid], a1 = 0.f, a2 = 0.f, a3 = 0.f;
        const float4* w4 = (const float4*)&head_w[tid * HH];
        const float4* h4 = (const float4*)hf;
#pragma unroll
        for (int j4 = 0; j4 < 32; ++j4) {
            float4 wv = w4[j4];
            float4 hv = h4[j4];
            a0 = fmaf(wv.x, hv.x, a0);
            a1 = fmaf(wv.y, hv.y, a1);
            a2 = fmaf(wv.z, hv.z, a2);
            a3 = fmaf(wv.w, hv.w, a3);
        }
        out[b * NN + tid] = (a0 + a1) + (a2 + a3);
    }
}

// ---------------- launch ----------------
extern "C" void kernel_launch(void* const* d_in, const int* in_sizes, int n_in, void* d_out,
                              int out_size, void* d_ws, size_t ws_size, hipStream_t stream) {
    const float* x = (const float*)d_in[0];
    const int* ei = (const int*)d_in[1];  // integer inputs arrive as int32
    const float* gat_w = (const float*)d_in[2];
    const float* a_src = (const float*)d_in[3];
    const float* a_dst = (const float*)d_in[4];
    const float* gat_b = (const float*)d_in[5];
    const float* w_ih = (const float*)d_in[6];
    const float* w_hh = (const float*)d_in[7];
    const float* b_ih = (const float*)d_in[8];
    const float* b_hh = (const float*)d_in[9];
    const float* head_w = (const float*)d_in[10];
    const float* head_b = (const float*)d_in[11];
    float* out = (float*)d_out;

    char* ws = (char*)d_ws;
    float* xt = (float*)(ws + 0);                      // 2,048,000 (dead after k_gat)
    float* s = (float*)(ws + 2048000u);                // 2,048,000 (dead after k_gemm)
    float* G2 = (float*)(ws + 4096000u);               // 16*1024*512*4 = 33,554,432
    _Float16* whh_h = (_Float16*)(ws + 37650432u);     // 131,072
    _Float16* w_h = (_Float16*)(ws + 37912576u);       // 16,384,000
    char* base2 = ws + 54296576u;                      // misc 65,536
    int* offsets = (int*)(base2);
    int* esrc = (int*)(base2 + 4096);
    float* scal = (float*)(base2 + 45056);
    float* Xg = (float*)(ws + 0);                      // 2,097,152 [bs][512] — overlaps xt+s
                                                       // (both dead by k_reduce; stream-ordered)

    k_prep<<<4864, 256, 0, stream>>>(x, xt, w_hh, whh_h, w_ih, w_h);
    k_graph<<<1, 512, 0, stream>>>(ei, gat_w, a_src, a_dst, offsets, esrc, scal);
    k_gat<<<dim3(BS / 256, NN), 256, 0, stream>>>(xt, offsets, esrc, scal, s);
    k_gemm_mfma<<<dim3(8, 4, KS), 256, 0, stream>>>(w_h, s, gat_w, gat_b, G2);
    k_reduce<<<512, 256, 0, stream>>>(G2, b_ih, b_hh, Xg);
    k_lstm_dot2<<<NB, 512, 0, stream>>>(Xg, whh_h, head_w, head_b, out);
}